// Round 31
// baseline (291.473 us; speedup 1.0000x reference)
//
#include <hip/hip_runtime.h>

#define N_NODES 100000
#define N_EDGES 800000
#define SCAN_CHUNK 1024
#define SCAN_NB ((N_NODES + SCAN_CHUNK - 1) / SCAN_CHUNK)   // 98
#define ROWS_PER_BLK 391
#define TILES 25            // 25*16 = 400 >= 391
#define FILL_RANGES 16
#define FILL_SLICES 256
#define SLICE_SZ (N_EDGES / FILL_SLICES)   // 3125

typedef __attribute__((ext_vector_type(8))) _Float16 f16x8;
typedef __attribute__((ext_vector_type(4))) _Float16 f16x4;
typedef __attribute__((ext_vector_type(4))) float f32x4;

// ---------------- degree count ----------------
__global__ void count_int_k(const int* __restrict__ dst, int* __restrict__ cnt, int E) {
    int i = blockIdx.x * blockDim.x + threadIdx.x;
    if (i < E) atomicAdd(&cnt[dst[i]], 1);
}

// ---------------- scan pass 1 ----------------
__global__ __launch_bounds__(256) void scan1_k(const int* __restrict__ cnt,
                                               int* __restrict__ offs,
                                               int* __restrict__ bsums, int N) {
    __shared__ int s[256];
    int t = threadIdx.x;
    int base = blockIdx.x * SCAN_CHUNK + t * 4;
    int v0 = (base + 0 < N) ? cnt[base + 0] : 0;
    int v1 = (base + 1 < N) ? cnt[base + 1] : 0;
    int v2 = (base + 2 < N) ? cnt[base + 2] : 0;
    int v3 = (base + 3 < N) ? cnt[base + 3] : 0;
    int tsum = v0 + v1 + v2 + v3;
    s[t] = tsum;
    __syncthreads();
    for (int off = 1; off < 256; off <<= 1) {
        int val = (t >= off) ? s[t - off] : 0;
        __syncthreads();
        s[t] += val;
        __syncthreads();
    }
    int excl = s[t] - tsum;
    if (base + 0 < N) offs[base + 0] = excl;
    if (base + 1 < N) offs[base + 1] = excl + v0;
    if (base + 2 < N) offs[base + 2] = excl + v0 + v1;
    if (base + 3 < N) offs[base + 3] = excl + v0 + v1 + v2;
    if (t == 255) bsums[blockIdx.x] = s[255];
}

// ---------------- scan pass 2 ----------------
__global__ __launch_bounds__(256) void scan2_k(const int* __restrict__ bsums,
                                               int* __restrict__ boffs, int nb) {
    __shared__ int s[256];
    int t = threadIdx.x;
    int v = (t < nb) ? bsums[t] : 0;
    s[t] = v;
    __syncthreads();
    for (int off = 1; off < 256; off <<= 1) {
        int val = (t >= off) ? s[t - off] : 0;
        __syncthreads();
        s[t] += val;
        __syncthreads();
    }
    if (t < nb) boffs[t] = s[t] - v;
}

// ---------------- scan pass 3 ----------------
__global__ void scan3_k(int* __restrict__ offs, int* __restrict__ cursor,
                        const int* __restrict__ boffs, int N, int E) {
    int i = blockIdx.x * blockDim.x + threadIdx.x;
    if (i < N) {
        int v = offs[i] + boffs[i >> 10];
        offs[i] = v;
        cursor[i] = v;
    }
    if (i == 0) offs[N] = E;
}

// ---------------- dst-range-partitioned bucket fill ----------------
__global__ __launch_bounds__(256) void fill_part_k(const int* __restrict__ src,
                                                   const int* __restrict__ dst,
                                                   int* __restrict__ cursor,
                                                   int* __restrict__ perm, int E) {
    int bid = blockIdx.x;
    int r = bid & (FILL_RANGES - 1);
    int s = bid >> 4;
    int lo = r * (N_NODES / FILL_RANGES);
    int hi = (r == FILL_RANGES - 1) ? N_NODES : lo + (N_NODES / FILL_RANGES);
    int e0 = s * SLICE_SZ;
    int e1 = min(e0 + SLICE_SZ, E);
    for (int e = e0 + (int)threadIdx.x; e < e1; e += 256) {
        int d = dst[e];
        if (d >= lo && d < hi) {
            int slot = atomicAdd(&cursor[d], 1);
            perm[slot] = src[e];
        }
    }
}

// ---------------- bulk f32 -> f16 (x features) ----------------
__global__ __launch_bounds__(256) void cvt_f16_k(const float* __restrict__ in,
                                                 _Float16* __restrict__ outp, int n8) {
    int i = blockIdx.x * blockDim.x + threadIdx.x;
    if (i >= n8) return;
    const float4* p = (const float4*)in + (long long)i * 2;
    float4 v0 = p[0], v1 = p[1];
    f16x8 h;
    h[0] = (_Float16)v0.x; h[1] = (_Float16)v0.y;
    h[2] = (_Float16)v0.z; h[3] = (_Float16)v0.w;
    h[4] = (_Float16)v1.x; h[5] = (_Float16)v1.y;
    h[6] = (_Float16)v1.z; h[7] = (_Float16)v1.w;
    *(f16x8*)&outp[(long long)i * 8] = h;
}

// ---------------- fused 4-weight f32 -> f16 ----------------
__global__ __launch_bounds__(256) void cvt_w4_k(const float* __restrict__ w0,
                                                const float* __restrict__ w1,
                                                const float* __restrict__ w2,
                                                const float* __restrict__ w3,
                                                _Float16* __restrict__ o0,
                                                _Float16* __restrict__ o1,
                                                _Float16* __restrict__ o2,
                                                _Float16* __restrict__ o3) {
    int i = blockIdx.x * blockDim.x + threadIdx.x;   // 0..16383
    int wsel = i >> 12;
    int j = i & 4095;
    const float* in; _Float16* outp;
    if (wsel == 0)      { in = w0; outp = o0; }
    else if (wsel == 1) { in = w1; outp = o1; }
    else if (wsel == 2) { in = w2; outp = o2; }
    else                { in = w3; outp = o3; }
    const float4* p = (const float4*)in + (long long)j * 2;
    float4 v0 = p[0], v1 = p[1];
    f16x8 h;
    h[0] = (_Float16)v0.x; h[1] = (_Float16)v0.y;
    h[2] = (_Float16)v0.z; h[3] = (_Float16)v0.w;
    h[4] = (_Float16)v1.x; h[5] = (_Float16)v1.y;
    h[6] = (_Float16)v1.z; h[7] = (_Float16)v1.w;
    *(f16x8*)&outp[(long long)j * 8] = h;
}

// ---------------- gather-mean, 16 lanes/node x f16x8 ----------------
__global__ __launch_bounds__(256) void aggmean_k(const _Float16* __restrict__ feat16,
                                                 const int* __restrict__ perm,
                                                 const int* __restrict__ offs,
                                                 _Float16* __restrict__ m16, int N) {
    int tid = threadIdx.x;
    int node = blockIdx.x * 16 + (tid >> 4);
    int q = tid & 15;
    if (node >= N) return;
    int beg = offs[node], end = offs[node + 1];
    float a[8], b[8];
#pragma unroll
    for (int k = 0; k < 8; k++) { a[k] = 0.0f; b[k] = 0.0f; }
    int i = beg;
    for (; i + 1 < end; i += 2) {
        f16x8 v0 = *(const f16x8*)&feat16[(long long)perm[i] * 128 + q * 8];
        f16x8 v1 = *(const f16x8*)&feat16[(long long)perm[i + 1] * 128 + q * 8];
#pragma unroll
        for (int k = 0; k < 8; k++) { a[k] += (float)v0[k]; b[k] += (float)v1[k]; }
    }
    if (i < end) {
        f16x8 v0 = *(const f16x8*)&feat16[(long long)perm[i] * 128 + q * 8];
#pragma unroll
        for (int k = 0; k < 8; k++) a[k] += (float)v0[k];
    }
    float rc = 1.0f / fmaxf((float)(end - beg), 1.0f);
    f16x8 v;
#pragma unroll
    for (int k = 0; k < 8; k++) v[k] = (_Float16)((a[k] + b[k]) * rc);
    *(f16x8*)&m16[(long long)node * 128 + q * 8] = v;
}

// ---------------- layer-2 agg fused epilogue ----------------
__global__ __launch_bounds__(256) void aggout_k(const _Float16* __restrict__ g16,
                                                const int* __restrict__ perm,
                                                const int* __restrict__ offs,
                                                const _Float16* __restrict__ r2h,
                                                const float* __restrict__ b2l,
                                                float* __restrict__ out, int N) {
    int tid = threadIdx.x;
    int node = blockIdx.x * 16 + (tid >> 4);
    int q = tid & 15;
    if (node >= N) return;
    int beg = offs[node], end = offs[node + 1];
    float a[8], b[8];
#pragma unroll
    for (int k = 0; k < 8; k++) { a[k] = 0.0f; b[k] = 0.0f; }
    int i = beg;
    for (; i + 1 < end; i += 2) {
        f16x8 v0 = *(const f16x8*)&g16[(long long)perm[i] * 128 + q * 8];
        f16x8 v1 = *(const f16x8*)&g16[(long long)perm[i + 1] * 128 + q * 8];
#pragma unroll
        for (int k = 0; k < 8; k++) { a[k] += (float)v0[k]; b[k] += (float)v1[k]; }
    }
    if (i < end) {
        f16x8 v0 = *(const f16x8*)&g16[(long long)perm[i] * 128 + q * 8];
#pragma unroll
        for (int k = 0; k < 8; k++) a[k] += (float)v0[k];
    }
    float rc = 1.0f / fmaxf((float)(end - beg), 1.0f);
    f16x8 rv = *(const f16x8*)&r2h[(long long)node * 128 + q * 8];
    float4 bv0 = ((const float4*)b2l)[q * 2];
    float4 bv1 = ((const float4*)b2l)[q * 2 + 1];
    float4 o0, o1;
    o0.x = (a[0] + b[0]) * rc + (float)rv[0] + bv0.x;
    o0.y = (a[1] + b[1]) * rc + (float)rv[1] + bv0.y;
    o0.z = (a[2] + b[2]) * rc + (float)rv[2] + bv0.z;
    o0.w = (a[3] + b[3]) * rc + (float)rv[3] + bv0.w;
    o1.x = (a[4] + b[4]) * rc + (float)rv[4] + bv1.x;
    o1.y = (a[5] + b[5]) * rc + (float)rv[5] + bv1.y;
    o1.z = (a[6] + b[6]) * rc + (float)rv[6] + bv1.z;
    o1.w = (a[7] + b[7]) * rc + (float)rv[7] + bv1.w;
    ((float4*)out)[(long long)node * 32 + q * 2]     = o0;
    ((float4*)out)[(long long)node * 32 + q * 2 + 1] = o1;
}

// ---------------- async global->LDS, 16B/lane ----------------
__device__ inline void gload16(const void* g, void* l) {
    __builtin_amdgcn_global_load_lds(
        (const __attribute__((address_space(1))) unsigned int*)g,
        (__attribute__((address_space(3))) unsigned int*)l,
        16, 0, 0);
}

// ========== quarter-col resident-B stream-M fp16 MFMA GEMM, 3 blocks/CU ==========
// 1024 blocks = 256 row-groups x 4 col-quarters. Block (rb, cb): rows
// rb*391..+391, cols cb*64..+64. B-quarter (64 cols x 256 k) resident in
// LDS = 32 KiB; A ring 2 x 8 KiB -> 48 KiB -> 3 independent blocks/CU.
// 256 threads = 4 waves; wave w: col = cb*64 + w*16 + lr (1 frag, f32x4 acc).
// Per tile: STAGE_A(t+1) = 2 gload16/wave -> vmcnt(2) -> barrier -> 8 MFMA
// -> stores -> barrier. Each gload16 covers 2 rows/cols x 32 chunks = 1 KiB
// = 512 halfs -> LDS dest = seg*512 (r30's NaN was seg*1024 OOB).
// Swizzle: chunk c of row/col r at slot c^(r&15).
template <int LAYER>
__global__ __launch_bounds__(256, 3) void gemm_stream_k(
        const _Float16* __restrict__ Ap0, const _Float16* __restrict__ Ap1,
        const _Float16* __restrict__ Bp0, const _Float16* __restrict__ Bp1,
        const float* __restrict__ bias,
        _Float16* __restrict__ O1h,
        _Float16* __restrict__ OH, int N) {
    __shared__ _Float16 Bs[64 * 256];      // 32 KiB
    __shared__ _Float16 As2[2][16 * 256];  // 2 x 8 KiB

    const int rb = blockIdx.x >> 2;
    const int cb = blockIdx.x & 3;         // col quarter
    const int mbase = rb * ROWS_PER_BLK;
    const int rend = min(mbase + ROWS_PER_BLK, N);
    const int tid = threadIdx.x;
    const int lane = tid & 63;
    const int wid = tid >> 6;            // 0..3
    const int lr = lane & 15, lg = lane >> 4;
    const int r2 = lane >> 5;            // 0..1
    const int scs = lane & 31;           // chunk slot 0..31

    auto STAGE_A = [&](int tt, int bi) {
#pragma unroll
        for (int it = 0; it < 2; ++it) {
            int seg = wid * 2 + it;            // 0..7 (2 rows each)
            int lrow = seg * 2 + r2;           // 0..15
            int ck = scs ^ (lrow & 15);
            int gn = mbase + tt * 16 + lrow;
            if (gn < N) {
                const _Float16* src;
                if constexpr (LAYER == 1)
                    src = (ck < 16) ? (Ap0 + (long long)gn * 128 + ck * 8)
                                    : (Ap1 + (long long)gn * 128 + (ck - 16) * 8);
                else
                    src = Ap0 + (long long)gn * 256 + ck * 8;
                gload16(src, &As2[bi][seg * 512]);
            }
        }
    };

    // ---- resident B-quarter load: 32 segs of 2 local cols, 8 per wave ----
#pragma unroll
    for (int it = 0; it < 8; ++it) {
        int seg = wid * 8 + it;                // 0..31
        int lcol = seg * 2 + r2;               // 0..63
        int col = cb * 64 + lcol;              // global output col
        int ck = scs ^ (lcol & 15);            // pre-swizzled source chunk
        const _Float16* src;
        if constexpr (LAYER == 1)
            src = (ck < 16) ? (Bp0 + (long long)col * 128 + ck * 8)
                            : (Bp1 + (long long)col * 128 + (ck - 16) * 8);
        else
            src = ((cb < 2) ? Bp0 : Bp1)
                  + (long long)((cb & 1) * 64 + lcol) * 256 + ck * 8;
        gload16(src, &Bs[seg * 512]);
    }
    STAGE_A(0, 0);
    asm volatile("s_waitcnt vmcnt(0)" ::: "memory");
    __builtin_amdgcn_s_barrier();

#pragma unroll 1
    for (int t = 0; t < TILES; ++t) {
        if (t + 1 < TILES) {
            STAGE_A(t + 1, (t + 1) & 1);
            asm volatile("s_waitcnt vmcnt(2)" ::: "memory");
        } else {
            asm volatile("s_waitcnt vmcnt(0)" ::: "memory");
        }
        __builtin_amdgcn_sched_barrier(0);
        __builtin_amdgcn_s_barrier();      // tile-t data in LDS

        const _Float16* Ab = &As2[t & 1][0];
        f32x4 acc = (f32x4)0.0f;
#pragma unroll
        for (int ks = 0; ks < 8; ++ks) {
            int c = ks * 4 + lg;               // k-chunk 0..31
            f16x8 af = *(const f16x8*)&Ab[lr * 256 + (c ^ lr) * 8];
            int lcol = wid * 16 + lr;          // local col 0..63
            f16x8 bf = *(const f16x8*)&Bs[lcol * 256 + (c ^ (lcol & 15)) * 8];
            acc = __builtin_amdgcn_mfma_f32_16x16x32_f16(af, bf, acc, 0, 0, 0);
        }

        // ---- epilogue ----
        {
            int col = cb * 64 + wid * 16 + lr;
            if constexpr (LAYER == 1) {
                float bv = bias[col];
#pragma unroll
                for (int j = 0; j < 4; ++j) {
                    int row = mbase + t * 16 + lg * 4 + j;
                    if (row < rend)
                        OH[(long long)row * 256 + col] =
                            (_Float16)fmaxf(acc[j] + bv, 0.0f);
                }
            } else {
                _Float16* dp = (cb < 2) ? OH : O1h;        // g | r2
                int dcol = (cb & 1) * 64 + wid * 16 + lr;  // 0..127
#pragma unroll
                for (int j = 0; j < 4; ++j) {
                    int row = mbase + t * 16 + lg * 4 + j;
                    if (row < rend)
                        dp[(long long)row * 128 + dcol] = (_Float16)acc[j];
                }
            }
        }
        __builtin_amdgcn_s_barrier();      // readers done before buf reuse
    }
}

extern "C" void kernel_launch(void* const* d_in, const int* in_sizes, int n_in,
                              void* d_out, int out_size, void* d_ws, size_t ws_size,
                              hipStream_t stream) {
    const float* x   = (const float*)d_in[0];
    const int*   ei  = (const int*)d_in[1];     // [2, E]
    const float* W1l = (const float*)d_in[2];
    const float* b1l = (const float*)d_in[3];
    const float* W1r = (const float*)d_in[4];
    const float* W2l = (const float*)d_in[5];
    const float* b2l = (const float*)d_in[6];
    const float* W2r = (const float*)d_in[7];
    float* out = (float*)d_out;

    const int N = N_NODES, E = N_EDGES;
    const int* srcI = ei;
    const int* dstI = ei + E;

    char* ws = (char*)d_ws;
    size_t off = 0;
    auto alloc = [&](size_t bytes) {
        size_t o = off;
        off += (bytes + 511) & ~(size_t)511;
        return o;
    };
    size_t off_cnt   = alloc((size_t)N * 4);
    size_t off_offs  = alloc((size_t)(N + 1) * 4);
    size_t off_cur   = alloc((size_t)N * 4);
    size_t off_bsum  = alloc((size_t)SCAN_NB * 4);
    size_t off_boff  = alloc((size_t)SCAN_NB * 4);
    size_t off_perm  = alloc((size_t)E * 4);
    size_t off_x16   = alloc((size_t)N * 128 * 2);
    size_t off_m16   = alloc((size_t)N * 128 * 2);
    size_t off_h16   = alloc((size_t)N * 256 * 2);
    size_t off_g16   = alloc((size_t)N * 128 * 2);
    size_t off_r2    = alloc((size_t)N * 128 * 2);
    size_t off_w     = alloc((size_t)4 * 32768 * 2);
    int*      cntI = (int*)(ws + off_cnt);
    int*      offs = (int*)(ws + off_offs);
    int*      cur  = (int*)(ws + off_cur);
    int*      bsum = (int*)(ws + off_bsum);
    int*      boff = (int*)(ws + off_boff);
    int*      perm = (int*)(ws + off_perm);
    _Float16* x16  = (_Float16*)(ws + off_x16);
    _Float16* m16  = (_Float16*)(ws + off_m16);
    _Float16* h16  = (_Float16*)(ws + off_h16);
    _Float16* g16  = (_Float16*)(ws + off_g16);
    _Float16* r2h  = (_Float16*)(ws + off_r2);
    _Float16* wbuf = (_Float16*)(ws + off_w);
    const int WSZ = 32768;
    _Float16* w1l16 = wbuf;            _Float16* w1r16 = wbuf + WSZ;
    _Float16* w2l16 = wbuf + 2 * WSZ;  _Float16* w2r16 = wbuf + 3 * WSZ;

    // ---- CSR build ----
    (void)hipMemsetAsync(cntI, 0, (size_t)N * 4, stream);
    count_int_k<<<(E + 255) / 256, 256, 0, stream>>>(dstI, cntI, E);
    scan1_k<<<SCAN_NB, 256, 0, stream>>>(cntI, offs, bsum, N);
    scan2_k<<<1, 256, 0, stream>>>(bsum, boff, SCAN_NB);
    scan3_k<<<(N + 255) / 256, 256, 0, stream>>>(offs, cur, boff, N, E);
    fill_part_k<<<FILL_RANGES * FILL_SLICES, 256, 0, stream>>>(srcI, dstI, cur, perm, E);

    // ---- f16 conversions ----
    {
        int n8x = N * 16;
        cvt_f16_k<<<(n8x + 255) / 256, 256, 0, stream>>>(x, x16, n8x);
        cvt_w4_k<<<16384 / 256, 256, 0, stream>>>(W1l, W1r, W2l, W2r,
                                                  w1l16, w1r16, w2l16, w2r16);
    }

    // ---- layer 1 ----
    aggmean_k<<<(N + 15) / 16, 256, 0, stream>>>(x16, perm, offs, m16, N);
    gemm_stream_k<1><<<1024, 256, 0, stream>>>(m16, x16, w1l16, w1r16,
                                               b1l, nullptr, h16, N);

    // ---- layer 2 ----
    gemm_stream_k<2><<<1024, 256, 0, stream>>>(h16, h16, w2l16, w2r16,
                                               nullptr, r2h, g16, N);
    aggout_k<<<(N + 15) / 16, 256, 0, stream>>>(g16, perm, offs, r2h, b2l, out, N);
}

// Round 32
// 244.683 us; speedup vs baseline: 1.1912x; 1.1912x over previous
//
#include <hip/hip_runtime.h>

#define N_NODES 100000
#define N_EDGES 800000
#define SCAN_CHUNK 1024
#define SCAN_NB ((N_NODES + SCAN_CHUNK - 1) / SCAN_CHUNK)   // 98
#define ROWS_PER_BLK 391
#define TILES 25            // 25*16 = 400 >= 391
#define FILL_RANGES 16
#define FILL_SLICES 256
#define SLICE_SZ (N_EDGES / FILL_SLICES)   // 3125

typedef __attribute__((ext_vector_type(8))) _Float16 f16x8;
typedef __attribute__((ext_vector_type(4))) _Float16 f16x4;
typedef __attribute__((ext_vector_type(4))) float f32x4;

// ---------------- degree count ----------------
__global__ void count_int_k(const int* __restrict__ dst, int* __restrict__ cnt, int E) {
    int i = blockIdx.x * blockDim.x + threadIdx.x;
    if (i < E) atomicAdd(&cnt[dst[i]], 1);
}

// ---------------- scan pass 1 ----------------
__global__ __launch_bounds__(256) void scan1_k(const int* __restrict__ cnt,
                                               int* __restrict__ offs,
                                               int* __restrict__ bsums, int N) {
    __shared__ int s[256];
    int t = threadIdx.x;
    int base = blockIdx.x * SCAN_CHUNK + t * 4;
    int v0 = (base + 0 < N) ? cnt[base + 0] : 0;
    int v1 = (base + 1 < N) ? cnt[base + 1] : 0;
    int v2 = (base + 2 < N) ? cnt[base + 2] : 0;
    int v3 = (base + 3 < N) ? cnt[base + 3] : 0;
    int tsum = v0 + v1 + v2 + v3;
    s[t] = tsum;
    __syncthreads();
    for (int off = 1; off < 256; off <<= 1) {
        int val = (t >= off) ? s[t - off] : 0;
        __syncthreads();
        s[t] += val;
        __syncthreads();
    }
    int excl = s[t] - tsum;
    if (base + 0 < N) offs[base + 0] = excl;
    if (base + 1 < N) offs[base + 1] = excl + v0;
    if (base + 2 < N) offs[base + 2] = excl + v0 + v1;
    if (base + 3 < N) offs[base + 3] = excl + v0 + v1 + v2;
    if (t == 255) bsums[blockIdx.x] = s[255];
}

// ---------------- scan pass 2 ----------------
__global__ __launch_bounds__(256) void scan2_k(const int* __restrict__ bsums,
                                               int* __restrict__ boffs, int nb) {
    __shared__ int s[256];
    int t = threadIdx.x;
    int v = (t < nb) ? bsums[t] : 0;
    s[t] = v;
    __syncthreads();
    for (int off = 1; off < 256; off <<= 1) {
        int val = (t >= off) ? s[t - off] : 0;
        __syncthreads();
        s[t] += val;
        __syncthreads();
    }
    if (t < nb) boffs[t] = s[t] - v;
}

// ---------------- scan pass 3 ----------------
__global__ void scan3_k(int* __restrict__ offs, int* __restrict__ cursor,
                        const int* __restrict__ boffs, int N, int E) {
    int i = blockIdx.x * blockDim.x + threadIdx.x;
    if (i < N) {
        int v = offs[i] + boffs[i >> 10];
        offs[i] = v;
        cursor[i] = v;
    }
    if (i == 0) offs[N] = E;
}

// ---------------- dst-range-partitioned bucket fill ----------------
__global__ __launch_bounds__(256) void fill_part_k(const int* __restrict__ src,
                                                   const int* __restrict__ dst,
                                                   int* __restrict__ cursor,
                                                   int* __restrict__ perm, int E) {
    int bid = blockIdx.x;
    int r = bid & (FILL_RANGES - 1);
    int s = bid >> 4;
    int lo = r * (N_NODES / FILL_RANGES);
    int hi = (r == FILL_RANGES - 1) ? N_NODES : lo + (N_NODES / FILL_RANGES);
    int e0 = s * SLICE_SZ;
    int e1 = min(e0 + SLICE_SZ, E);
    for (int e = e0 + (int)threadIdx.x; e < e1; e += 256) {
        int d = dst[e];
        if (d >= lo && d < hi) {
            int slot = atomicAdd(&cursor[d], 1);
            perm[slot] = src[e];
        }
    }
}

// ---------------- bulk f32 -> f16 (x features) ----------------
__global__ __launch_bounds__(256) void cvt_f16_k(const float* __restrict__ in,
                                                 _Float16* __restrict__ outp, int n8) {
    int i = blockIdx.x * blockDim.x + threadIdx.x;
    if (i >= n8) return;
    const float4* p = (const float4*)in + (long long)i * 2;
    float4 v0 = p[0], v1 = p[1];
    f16x8 h;
    h[0] = (_Float16)v0.x; h[1] = (_Float16)v0.y;
    h[2] = (_Float16)v0.z; h[3] = (_Float16)v0.w;
    h[4] = (_Float16)v1.x; h[5] = (_Float16)v1.y;
    h[6] = (_Float16)v1.z; h[7] = (_Float16)v1.w;
    *(f16x8*)&outp[(long long)i * 8] = h;
}

// ---------------- fused 4-weight f32 -> f16 ----------------
__global__ __launch_bounds__(256) void cvt_w4_k(const float* __restrict__ w0,
                                                const float* __restrict__ w1,
                                                const float* __restrict__ w2,
                                                const float* __restrict__ w3,
                                                _Float16* __restrict__ o0,
                                                _Float16* __restrict__ o1,
                                                _Float16* __restrict__ o2,
                                                _Float16* __restrict__ o3) {
    int i = blockIdx.x * blockDim.x + threadIdx.x;   // 0..16383
    int wsel = i >> 12;
    int j = i & 4095;
    const float* in; _Float16* outp;
    if (wsel == 0)      { in = w0; outp = o0; }
    else if (wsel == 1) { in = w1; outp = o1; }
    else if (wsel == 2) { in = w2; outp = o2; }
    else                { in = w3; outp = o3; }
    const float4* p = (const float4*)in + (long long)j * 2;
    float4 v0 = p[0], v1 = p[1];
    f16x8 h;
    h[0] = (_Float16)v0.x; h[1] = (_Float16)v0.y;
    h[2] = (_Float16)v0.z; h[3] = (_Float16)v0.w;
    h[4] = (_Float16)v1.x; h[5] = (_Float16)v1.y;
    h[6] = (_Float16)v1.z; h[7] = (_Float16)v1.w;
    *(f16x8*)&outp[(long long)j * 8] = h;
}

// ---------------- gather-mean, 16 lanes/node x f16x8 ----------------
__global__ __launch_bounds__(256) void aggmean_k(const _Float16* __restrict__ feat16,
                                                 const int* __restrict__ perm,
                                                 const int* __restrict__ offs,
                                                 _Float16* __restrict__ m16, int N) {
    int tid = threadIdx.x;
    int node = blockIdx.x * 16 + (tid >> 4);
    int q = tid & 15;
    if (node >= N) return;
    int beg = offs[node], end = offs[node + 1];
    float a[8], b[8];
#pragma unroll
    for (int k = 0; k < 8; k++) { a[k] = 0.0f; b[k] = 0.0f; }
    int i = beg;
    for (; i + 1 < end; i += 2) {
        f16x8 v0 = *(const f16x8*)&feat16[(long long)perm[i] * 128 + q * 8];
        f16x8 v1 = *(const f16x8*)&feat16[(long long)perm[i + 1] * 128 + q * 8];
#pragma unroll
        for (int k = 0; k < 8; k++) { a[k] += (float)v0[k]; b[k] += (float)v1[k]; }
    }
    if (i < end) {
        f16x8 v0 = *(const f16x8*)&feat16[(long long)perm[i] * 128 + q * 8];
#pragma unroll
        for (int k = 0; k < 8; k++) a[k] += (float)v0[k];
    }
    float rc = 1.0f / fmaxf((float)(end - beg), 1.0f);
    f16x8 v;
#pragma unroll
    for (int k = 0; k < 8; k++) v[k] = (_Float16)((a[k] + b[k]) * rc);
    *(f16x8*)&m16[(long long)node * 128 + q * 8] = v;
}

// ---------------- layer-2 agg fused epilogue ----------------
__global__ __launch_bounds__(256) void aggout_k(const _Float16* __restrict__ g16,
                                                const int* __restrict__ perm,
                                                const int* __restrict__ offs,
                                                const _Float16* __restrict__ r2h,
                                                const float* __restrict__ b2l,
                                                float* __restrict__ out, int N) {
    int tid = threadIdx.x;
    int node = blockIdx.x * 16 + (tid >> 4);
    int q = tid & 15;
    if (node >= N) return;
    int beg = offs[node], end = offs[node + 1];
    float a[8], b[8];
#pragma unroll
    for (int k = 0; k < 8; k++) { a[k] = 0.0f; b[k] = 0.0f; }
    int i = beg;
    for (; i + 1 < end; i += 2) {
        f16x8 v0 = *(const f16x8*)&g16[(long long)perm[i] * 128 + q * 8];
        f16x8 v1 = *(const f16x8*)&g16[(long long)perm[i + 1] * 128 + q * 8];
#pragma unroll
        for (int k = 0; k < 8; k++) { a[k] += (float)v0[k]; b[k] += (float)v1[k]; }
    }
    if (i < end) {
        f16x8 v0 = *(const f16x8*)&g16[(long long)perm[i] * 128 + q * 8];
#pragma unroll
        for (int k = 0; k < 8; k++) a[k] += (float)v0[k];
    }
    float rc = 1.0f / fmaxf((float)(end - beg), 1.0f);
    f16x8 rv = *(const f16x8*)&r2h[(long long)node * 128 + q * 8];
    float4 bv0 = ((const float4*)b2l)[q * 2];
    float4 bv1 = ((const float4*)b2l)[q * 2 + 1];
    float4 o0, o1;
    o0.x = (a[0] + b[0]) * rc + (float)rv[0] + bv0.x;
    o0.y = (a[1] + b[1]) * rc + (float)rv[1] + bv0.y;
    o0.z = (a[2] + b[2]) * rc + (float)rv[2] + bv0.z;
    o0.w = (a[3] + b[3]) * rc + (float)rv[3] + bv0.w;
    o1.x = (a[4] + b[4]) * rc + (float)rv[4] + bv1.x;
    o1.y = (a[5] + b[5]) * rc + (float)rv[5] + bv1.y;
    o1.z = (a[6] + b[6]) * rc + (float)rv[6] + bv1.z;
    o1.w = (a[7] + b[7]) * rc + (float)rv[7] + bv1.w;
    ((float4*)out)[(long long)node * 32 + q * 2]     = o0;
    ((float4*)out)[(long long)node * 32 + q * 2 + 1] = o1;
}

// ---------------- async global->LDS, 16B/lane ----------------
__device__ inline void gload16(const void* g, void* l) {
    __builtin_amdgcn_global_load_lds(
        (const __attribute__((address_space(1))) unsigned int*)g,
        (__attribute__((address_space(3))) unsigned int*)l,
        16, 0, 0);
}

// ========== col-split resident-B stream-M fp16 MFMA GEMM, 2 blocks/CU (r29 best) ==========
// 512 blocks = 256 row-groups x 2 col-halves. Block (rb, cb): rows
// rb*391..+391, cols cb*128..+128. B-half (128 cols x 256 k) resident in
// LDS = 64 KiB; A ring 2 x 8 KiB -> 80 KiB -> 2 independent blocks/CU.
// Per tile: STAGE_A(t+1) -> vmcnt(1) -> barrier -> 8 MFMA -> stores -> barrier.
// Swizzle: 16B chunk c of row/col r at slot c^(r&15); DMA pre-swizzled.
template <int LAYER>
__global__ __launch_bounds__(512, 2) void gemm_stream_k(
        const _Float16* __restrict__ Ap0, const _Float16* __restrict__ Ap1,
        const _Float16* __restrict__ Bp0, const _Float16* __restrict__ Bp1,
        const float* __restrict__ bias,
        _Float16* __restrict__ O1h,
        _Float16* __restrict__ OH, int N) {
    __shared__ _Float16 Bs[128 * 256];     // 64 KiB
    __shared__ _Float16 As2[2][16 * 256];  // 2 x 8 KiB

    const int rb = blockIdx.x >> 1;
    const int cb = blockIdx.x & 1;         // col half
    const int mbase = rb * ROWS_PER_BLK;
    const int rend = min(mbase + ROWS_PER_BLK, N);
    const int tid = threadIdx.x;
    const int lane = tid & 63;
    const int wid = tid >> 6;            // 0..7: cols cb*128 + wid*16 .. +16
    const int lr = lane & 15, lg = lane >> 4;
    const int r2 = lane >> 5;            // 0..1
    const int scs = lane & 31;           // chunk slot 0..31

    auto STAGE_A = [&](int tt, int bi) {
        int lrow = wid * 2 + r2;               // 0..15
        int ck = scs ^ (lrow & 15);
        int gn = mbase + tt * 16 + lrow;
        if (gn < N) {
            const _Float16* src;
            if constexpr (LAYER == 1)
                src = (ck < 16) ? (Ap0 + (long long)gn * 128 + ck * 8)
                                : (Ap1 + (long long)gn * 128 + (ck - 16) * 8);
            else
                src = Ap0 + (long long)gn * 256 + ck * 8;
            gload16(src, &As2[bi][wid * 512]);
        }
    };

    // ---- resident B-half load: 64 segs of 2 local cols, 8 per wave ----
#pragma unroll
    for (int it = 0; it < 8; ++it) {
        int seg = wid * 8 + it;                // 0..63
        int lcol = seg * 2 + r2;               // 0..127
        int col = cb * 128 + lcol;             // global output col
        int ck = scs ^ (lcol & 15);            // pre-swizzled source chunk
        const _Float16* src;
        if constexpr (LAYER == 1)
            src = (ck < 16) ? (Bp0 + (long long)col * 128 + ck * 8)
                            : (Bp1 + (long long)col * 128 + (ck - 16) * 8);
        else
            src = ((cb == 0) ? Bp0 : Bp1) + (long long)lcol * 256 + ck * 8;
        gload16(src, &Bs[seg * 512]);
    }
    STAGE_A(0, 0);
    asm volatile("s_waitcnt vmcnt(0)" ::: "memory");
    __builtin_amdgcn_s_barrier();

#pragma unroll 1
    for (int t = 0; t < TILES; ++t) {
        if (t + 1 < TILES) {
            STAGE_A(t + 1, (t + 1) & 1);
            asm volatile("s_waitcnt vmcnt(1)" ::: "memory");
        } else {
            asm volatile("s_waitcnt vmcnt(0)" ::: "memory");
        }
        __builtin_amdgcn_sched_barrier(0);
        __builtin_amdgcn_s_barrier();      // tile-t data in LDS

        const _Float16* Ab = &As2[t & 1][0];
        f32x4 acc = (f32x4)0.0f;
#pragma unroll
        for (int ks = 0; ks < 8; ++ks) {
            int c = ks * 4 + lg;               // k-chunk 0..31
            f16x8 af = *(const f16x8*)&Ab[lr * 256 + (c ^ lr) * 8];
            int lcol = wid * 16 + lr;          // local col 0..127
            f16x8 bf = *(const f16x8*)&Bs[lcol * 256 + (c ^ (lcol & 15)) * 8];
            acc = __builtin_amdgcn_mfma_f32_16x16x32_f16(af, bf, acc, 0, 0, 0);
        }

        // ---- epilogue ----
        {
            int col = cb * 128 + wid * 16 + lr;
            if constexpr (LAYER == 1) {
                float bv = bias[col];
#pragma unroll
                for (int j = 0; j < 4; ++j) {
                    int row = mbase + t * 16 + lg * 4 + j;
                    if (row < rend)
                        OH[(long long)row * 256 + col] =
                            (_Float16)fmaxf(acc[j] + bv, 0.0f);
                }
            } else {
                _Float16* dp = (cb == 0) ? OH : O1h;   // g | r2
                int dcol = wid * 16 + lr;              // 0..127
#pragma unroll
                for (int j = 0; j < 4; ++j) {
                    int row = mbase + t * 16 + lg * 4 + j;
                    if (row < rend)
                        dp[(long long)row * 128 + dcol] = (_Float16)acc[j];
                }
            }
        }
        __builtin_amdgcn_s_barrier();      // readers done before buf reuse
    }
}

extern "C" void kernel_launch(void* const* d_in, const int* in_sizes, int n_in,
                              void* d_out, int out_size, void* d_ws, size_t ws_size,
                              hipStream_t stream) {
    const float* x   = (const float*)d_in[0];
    const int*   ei  = (const int*)d_in[1];     // [2, E]
    const float* W1l = (const float*)d_in[2];
    const float* b1l = (const float*)d_in[3];
    const float* W1r = (const float*)d_in[4];
    const float* W2l = (const float*)d_in[5];
    const float* b2l = (const float*)d_in[6];
    const float* W2r = (const float*)d_in[7];
    float* out = (float*)d_out;

    const int N = N_NODES, E = N_EDGES;
    const int* srcI = ei;
    const int* dstI = ei + E;

    char* ws = (char*)d_ws;
    size_t off = 0;
    auto alloc = [&](size_t bytes) {
        size_t o = off;
        off += (bytes + 511) & ~(size_t)511;
        return o;
    };
    size_t off_cnt   = alloc((size_t)N * 4);
    size_t off_offs  = alloc((size_t)(N + 1) * 4);
    size_t off_cur   = alloc((size_t)N * 4);
    size_t off_bsum  = alloc((size_t)SCAN_NB * 4);
    size_t off_boff  = alloc((size_t)SCAN_NB * 4);
    size_t off_perm  = alloc((size_t)E * 4);
    size_t off_x16   = alloc((size_t)N * 128 * 2);
    size_t off_m16   = alloc((size_t)N * 128 * 2);
    size_t off_h16   = alloc((size_t)N * 256 * 2);
    size_t off_g16   = alloc((size_t)N * 128 * 2);
    size_t off_r2    = alloc((size_t)N * 128 * 2);
    size_t off_w     = alloc((size_t)4 * 32768 * 2);
    int*      cntI = (int*)(ws + off_cnt);
    int*      offs = (int*)(ws + off_offs);
    int*      cur  = (int*)(ws + off_cur);
    int*      bsum = (int*)(ws + off_bsum);
    int*      boff = (int*)(ws + off_boff);
    int*      perm = (int*)(ws + off_perm);
    _Float16* x16  = (_Float16*)(ws + off_x16);
    _Float16* m16  = (_Float16*)(ws + off_m16);
    _Float16* h16  = (_Float16*)(ws + off_h16);
    _Float16* g16  = (_Float16*)(ws + off_g16);
    _Float16* r2h  = (_Float16*)(ws + off_r2);
    _Float16* wbuf = (_Float16*)(ws + off_w);
    const int WSZ = 32768;
    _Float16* w1l16 = wbuf;            _Float16* w1r16 = wbuf + WSZ;
    _Float16* w2l16 = wbuf + 2 * WSZ;  _Float16* w2r16 = wbuf + 3 * WSZ;

    // ---- CSR build ----
    (void)hipMemsetAsync(cntI, 0, (size_t)N * 4, stream);
    count_int_k<<<(E + 255) / 256, 256, 0, stream>>>(dstI, cntI, E);
    scan1_k<<<SCAN_NB, 256, 0, stream>>>(cntI, offs, bsum, N);
    scan2_k<<<1, 256, 0, stream>>>(bsum, boff, SCAN_NB);
    scan3_k<<<(N + 255) / 256, 256, 0, stream>>>(offs, cur, boff, N, E);
    fill_part_k<<<FILL_RANGES * FILL_SLICES, 256, 0, stream>>>(srcI, dstI, cur, perm, E);

    // ---- f16 conversions ----
    {
        int n8x = N * 16;
        cvt_f16_k<<<(n8x + 255) / 256, 256, 0, stream>>>(x, x16, n8x);
        cvt_w4_k<<<16384 / 256, 256, 0, stream>>>(W1l, W1r, W2l, W2r,
                                                  w1l16, w1r16, w2l16, w2r16);
    }

    // ---- layer 1 ----
    aggmean_k<<<(N + 15) / 16, 256, 0, stream>>>(x16, perm, offs, m16, N);
    gemm_stream_k<1><<<512, 512, 0, stream>>>(m16, x16, w1l16, w1r16,
                                              b1l, nullptr, h16, N);

    // ---- layer 2 ----
    gemm_stream_k<2><<<512, 512, 0, stream>>>(h16, h16, w2l16, w2r16,
                                              nullptr, r2h, g16, N);
    aggout_k<<<(N + 15) / 16, 256, 0, stream>>>(g16, perm, offs, r2h, b2l, out, N);
}

// Round 33
// 238.650 us; speedup vs baseline: 1.2213x; 1.0253x over previous
//
#include <hip/hip_runtime.h>

#define N_NODES 100000
#define N_EDGES 800000
#define SCAN_CHUNK 1024
#define SCAN_NB ((N_NODES + SCAN_CHUNK - 1) / SCAN_CHUNK)   // 98
#define ROWS_PER_BLK 391
#define TILES 25            // 25*16 = 400 >= 391
#define FILL_RANGES 16
#define FILL_SLICES 256
#define SLICE_SZ (N_EDGES / FILL_SLICES)   // 3125

typedef __attribute__((ext_vector_type(8))) _Float16 f16x8;
typedef __attribute__((ext_vector_type(4))) _Float16 f16x4;
typedef __attribute__((ext_vector_type(4))) float f32x4;

// ---------------- degree count ----------------
__global__ void count_int_k(const int* __restrict__ dst, int* __restrict__ cnt, int E) {
    int i = blockIdx.x * blockDim.x + threadIdx.x;
    if (i < E) atomicAdd(&cnt[dst[i]], 1);
}

// ---------------- scan pass 1 ----------------
__global__ __launch_bounds__(256) void scan1_k(const int* __restrict__ cnt,
                                               int* __restrict__ offs,
                                               int* __restrict__ bsums, int N) {
    __shared__ int s[256];
    int t = threadIdx.x;
    int base = blockIdx.x * SCAN_CHUNK + t * 4;
    int v0 = (base + 0 < N) ? cnt[base + 0] : 0;
    int v1 = (base + 1 < N) ? cnt[base + 1] : 0;
    int v2 = (base + 2 < N) ? cnt[base + 2] : 0;
    int v3 = (base + 3 < N) ? cnt[base + 3] : 0;
    int tsum = v0 + v1 + v2 + v3;
    s[t] = tsum;
    __syncthreads();
    for (int off = 1; off < 256; off <<= 1) {
        int val = (t >= off) ? s[t - off] : 0;
        __syncthreads();
        s[t] += val;
        __syncthreads();
    }
    int excl = s[t] - tsum;
    if (base + 0 < N) offs[base + 0] = excl;
    if (base + 1 < N) offs[base + 1] = excl + v0;
    if (base + 2 < N) offs[base + 2] = excl + v0 + v1;
    if (base + 3 < N) offs[base + 3] = excl + v0 + v1 + v2;
    if (t == 255) bsums[blockIdx.x] = s[255];
}

// ---------------- scan pass 2 ----------------
__global__ __launch_bounds__(256) void scan2_k(const int* __restrict__ bsums,
                                               int* __restrict__ boffs, int nb) {
    __shared__ int s[256];
    int t = threadIdx.x;
    int v = (t < nb) ? bsums[t] : 0;
    s[t] = v;
    __syncthreads();
    for (int off = 1; off < 256; off <<= 1) {
        int val = (t >= off) ? s[t - off] : 0;
        __syncthreads();
        s[t] += val;
        __syncthreads();
    }
    if (t < nb) boffs[t] = s[t] - v;
}

// ---------------- scan pass 3 ----------------
__global__ void scan3_k(int* __restrict__ offs, int* __restrict__ cursor,
                        const int* __restrict__ boffs, int N, int E) {
    int i = blockIdx.x * blockDim.x + threadIdx.x;
    if (i < N) {
        int v = offs[i] + boffs[i >> 10];
        offs[i] = v;
        cursor[i] = v;
    }
    if (i == 0) offs[N] = E;
}

// ---------------- dst-range-partitioned bucket fill ----------------
__global__ __launch_bounds__(256) void fill_part_k(const int* __restrict__ src,
                                                   const int* __restrict__ dst,
                                                   int* __restrict__ cursor,
                                                   int* __restrict__ perm, int E) {
    int bid = blockIdx.x;
    int r = bid & (FILL_RANGES - 1);
    int s = bid >> 4;
    int lo = r * (N_NODES / FILL_RANGES);
    int hi = (r == FILL_RANGES - 1) ? N_NODES : lo + (N_NODES / FILL_RANGES);
    int e0 = s * SLICE_SZ;
    int e1 = min(e0 + SLICE_SZ, E);
    for (int e = e0 + (int)threadIdx.x; e < e1; e += 256) {
        int d = dst[e];
        if (d >= lo && d < hi) {
            int slot = atomicAdd(&cursor[d], 1);
            perm[slot] = src[e];
        }
    }
}

// ---------------- bulk f32 -> f16 (x features) ----------------
__global__ __launch_bounds__(256) void cvt_f16_k(const float* __restrict__ in,
                                                 _Float16* __restrict__ outp, int n8) {
    int i = blockIdx.x * blockDim.x + threadIdx.x;
    if (i >= n8) return;
    const float4* p = (const float4*)in + (long long)i * 2;
    float4 v0 = p[0], v1 = p[1];
    f16x8 h;
    h[0] = (_Float16)v0.x; h[1] = (_Float16)v0.y;
    h[2] = (_Float16)v0.z; h[3] = (_Float16)v0.w;
    h[4] = (_Float16)v1.x; h[5] = (_Float16)v1.y;
    h[6] = (_Float16)v1.z; h[7] = (_Float16)v1.w;
    *(f16x8*)&outp[(long long)i * 8] = h;
}

// ---------------- fused 4-weight f32 -> f16 ----------------
__global__ __launch_bounds__(256) void cvt_w4_k(const float* __restrict__ w0,
                                                const float* __restrict__ w1,
                                                const float* __restrict__ w2,
                                                const float* __restrict__ w3,
                                                _Float16* __restrict__ o0,
                                                _Float16* __restrict__ o1,
                                                _Float16* __restrict__ o2,
                                                _Float16* __restrict__ o3) {
    int i = blockIdx.x * blockDim.x + threadIdx.x;   // 0..16383
    int wsel = i >> 12;
    int j = i & 4095;
    const float* in; _Float16* outp;
    if (wsel == 0)      { in = w0; outp = o0; }
    else if (wsel == 1) { in = w1; outp = o1; }
    else if (wsel == 2) { in = w2; outp = o2; }
    else                { in = w3; outp = o3; }
    const float4* p = (const float4*)in + (long long)j * 2;
    float4 v0 = p[0], v1 = p[1];
    f16x8 h;
    h[0] = (_Float16)v0.x; h[1] = (_Float16)v0.y;
    h[2] = (_Float16)v0.z; h[3] = (_Float16)v0.w;
    h[4] = (_Float16)v1.x; h[5] = (_Float16)v1.y;
    h[6] = (_Float16)v1.z; h[7] = (_Float16)v1.w;
    *(f16x8*)&outp[(long long)j * 8] = h;
}

// ---------------- gather-mean, 16 lanes/node x f16x8 ----------------
__global__ __launch_bounds__(256) void aggmean_k(const _Float16* __restrict__ feat16,
                                                 const int* __restrict__ perm,
                                                 const int* __restrict__ offs,
                                                 _Float16* __restrict__ m16, int N) {
    int tid = threadIdx.x;
    int node = blockIdx.x * 16 + (tid >> 4);
    int q = tid & 15;
    if (node >= N) return;
    int beg = offs[node], end = offs[node + 1];
    float a[8], b[8];
#pragma unroll
    for (int k = 0; k < 8; k++) { a[k] = 0.0f; b[k] = 0.0f; }
    int i = beg;
    for (; i + 1 < end; i += 2) {
        f16x8 v0 = *(const f16x8*)&feat16[(long long)perm[i] * 128 + q * 8];
        f16x8 v1 = *(const f16x8*)&feat16[(long long)perm[i + 1] * 128 + q * 8];
#pragma unroll
        for (int k = 0; k < 8; k++) { a[k] += (float)v0[k]; b[k] += (float)v1[k]; }
    }
    if (i < end) {
        f16x8 v0 = *(const f16x8*)&feat16[(long long)perm[i] * 128 + q * 8];
#pragma unroll
        for (int k = 0; k < 8; k++) a[k] += (float)v0[k];
    }
    float rc = 1.0f / fmaxf((float)(end - beg), 1.0f);
    f16x8 v;
#pragma unroll
    for (int k = 0; k < 8; k++) v[k] = (_Float16)((a[k] + b[k]) * rc);
    *(f16x8*)&m16[(long long)node * 128 + q * 8] = v;
}

// ---------------- layer-2 agg fused epilogue ----------------
__global__ __launch_bounds__(256) void aggout_k(const _Float16* __restrict__ g16,
                                                const int* __restrict__ perm,
                                                const int* __restrict__ offs,
                                                const _Float16* __restrict__ r2h,
                                                const float* __restrict__ b2l,
                                                float* __restrict__ out, int N) {
    int tid = threadIdx.x;
    int node = blockIdx.x * 16 + (tid >> 4);
    int q = tid & 15;
    if (node >= N) return;
    int beg = offs[node], end = offs[node + 1];
    float a[8], b[8];
#pragma unroll
    for (int k = 0; k < 8; k++) { a[k] = 0.0f; b[k] = 0.0f; }
    int i = beg;
    for (; i + 1 < end; i += 2) {
        f16x8 v0 = *(const f16x8*)&g16[(long long)perm[i] * 128 + q * 8];
        f16x8 v1 = *(const f16x8*)&g16[(long long)perm[i + 1] * 128 + q * 8];
#pragma unroll
        for (int k = 0; k < 8; k++) { a[k] += (float)v0[k]; b[k] += (float)v1[k]; }
    }
    if (i < end) {
        f16x8 v0 = *(const f16x8*)&g16[(long long)perm[i] * 128 + q * 8];
#pragma unroll
        for (int k = 0; k < 8; k++) a[k] += (float)v0[k];
    }
    float rc = 1.0f / fmaxf((float)(end - beg), 1.0f);
    f16x8 rv = *(const f16x8*)&r2h[(long long)node * 128 + q * 8];
    float4 bv0 = ((const float4*)b2l)[q * 2];
    float4 bv1 = ((const float4*)b2l)[q * 2 + 1];
    float4 o0, o1;
    o0.x = (a[0] + b[0]) * rc + (float)rv[0] + bv0.x;
    o0.y = (a[1] + b[1]) * rc + (float)rv[1] + bv0.y;
    o0.z = (a[2] + b[2]) * rc + (float)rv[2] + bv0.z;
    o0.w = (a[3] + b[3]) * rc + (float)rv[3] + bv0.w;
    o1.x = (a[4] + b[4]) * rc + (float)rv[4] + bv1.x;
    o1.y = (a[5] + b[5]) * rc + (float)rv[5] + bv1.y;
    o1.z = (a[6] + b[6]) * rc + (float)rv[6] + bv1.z;
    o1.w = (a[7] + b[7]) * rc + (float)rv[7] + bv1.w;
    ((float4*)out)[(long long)node * 32 + q * 2]     = o0;
    ((float4*)out)[(long long)node * 32 + q * 2 + 1] = o1;
}

// ---------------- async global->LDS, 16B/lane ----------------
__device__ inline void gload16(const void* g, void* l) {
    __builtin_amdgcn_global_load_lds(
        (const __attribute__((address_space(1))) unsigned int*)g,
        (__attribute__((address_space(3))) unsigned int*)l,
        16, 0, 0);
}

// ========== col-split resident-B stream-M fp16 MFMA GEMM, 2 blocks/CU ==========
// 512 blocks; PAIR-COLOCATED mapping: rb = bid & 255, cb = bid >> 8 -> the two
// col-halves of a row-group are bids (rb, rb+256); 256 % 8 == 0 so the
// round-robin dispatcher places both on the SAME XCD -> the shared A-panel
// is fetched from HBM once and L2-hit by the partner (FETCH 51 -> ~28 MB).
// B-half (128 cols x 256 k) resident in LDS = 64 KiB; A ring 2 x 8 KiB ->
// 80 KiB -> 2 independent blocks/CU. Per tile: STAGE_A(t+1) -> vmcnt(1) ->
// barrier -> setprio(1) 8 MFMA setprio(0) -> stores -> barrier (T5: with two
// independent blocks/CU at uncorrelated phases, MFMA waves preempt the
// co-resident block's staging waves).
// Swizzle: 16B chunk c of row/col r at slot c^(r&15); DMA pre-swizzled.
template <int LAYER>
__global__ __launch_bounds__(512, 2) void gemm_stream_k(
        const _Float16* __restrict__ Ap0, const _Float16* __restrict__ Ap1,
        const _Float16* __restrict__ Bp0, const _Float16* __restrict__ Bp1,
        const float* __restrict__ bias,
        _Float16* __restrict__ O1h,
        _Float16* __restrict__ OH, int N) {
    __shared__ _Float16 Bs[128 * 256];     // 64 KiB
    __shared__ _Float16 As2[2][16 * 256];  // 2 x 8 KiB

    const int rb = blockIdx.x & 255;       // row-group
    const int cb = blockIdx.x >> 8;        // col half (partner = bid +/- 256, same XCD)
    const int mbase = rb * ROWS_PER_BLK;
    const int rend = min(mbase + ROWS_PER_BLK, N);
    const int tid = threadIdx.x;
    const int lane = tid & 63;
    const int wid = tid >> 6;            // 0..7: cols cb*128 + wid*16 .. +16
    const int lr = lane & 15, lg = lane >> 4;
    const int r2 = lane >> 5;            // 0..1
    const int scs = lane & 31;           // chunk slot 0..31

    auto STAGE_A = [&](int tt, int bi) {
        int lrow = wid * 2 + r2;               // 0..15
        int ck = scs ^ (lrow & 15);
        int gn = mbase + tt * 16 + lrow;
        if (gn < N) {
            const _Float16* src;
            if constexpr (LAYER == 1)
                src = (ck < 16) ? (Ap0 + (long long)gn * 128 + ck * 8)
                                : (Ap1 + (long long)gn * 128 + (ck - 16) * 8);
            else
                src = Ap0 + (long long)gn * 256 + ck * 8;
            gload16(src, &As2[bi][wid * 512]);
        }
    };

    // ---- resident B-half load: 64 segs of 2 local cols, 8 per wave ----
#pragma unroll
    for (int it = 0; it < 8; ++it) {
        int seg = wid * 8 + it;                // 0..63
        int lcol = seg * 2 + r2;               // 0..127
        int col = cb * 128 + lcol;             // global output col
        int ck = scs ^ (lcol & 15);            // pre-swizzled source chunk
        const _Float16* src;
        if constexpr (LAYER == 1)
            src = (ck < 16) ? (Bp0 + (long long)col * 128 + ck * 8)
                            : (Bp1 + (long long)col * 128 + (ck - 16) * 8);
        else
            src = ((cb == 0) ? Bp0 : Bp1) + (long long)lcol * 256 + ck * 8;
        gload16(src, &Bs[seg * 512]);
    }
    STAGE_A(0, 0);
    asm volatile("s_waitcnt vmcnt(0)" ::: "memory");
    __builtin_amdgcn_s_barrier();

#pragma unroll 1
    for (int t = 0; t < TILES; ++t) {
        if (t + 1 < TILES) {
            STAGE_A(t + 1, (t + 1) & 1);
            asm volatile("s_waitcnt vmcnt(1)" ::: "memory");
        } else {
            asm volatile("s_waitcnt vmcnt(0)" ::: "memory");
        }
        __builtin_amdgcn_sched_barrier(0);
        __builtin_amdgcn_s_barrier();      // tile-t data in LDS

        const _Float16* Ab = &As2[t & 1][0];
        f32x4 acc = (f32x4)0.0f;
        __builtin_amdgcn_s_setprio(1);
#pragma unroll
        for (int ks = 0; ks < 8; ++ks) {
            int c = ks * 4 + lg;               // k-chunk 0..31
            f16x8 af = *(const f16x8*)&Ab[lr * 256 + (c ^ lr) * 8];
            int lcol = wid * 16 + lr;          // local col 0..127
            f16x8 bf = *(const f16x8*)&Bs[lcol * 256 + (c ^ (lcol & 15)) * 8];
            acc = __builtin_amdgcn_mfma_f32_16x16x32_f16(af, bf, acc, 0, 0, 0);
        }
        __builtin_amdgcn_s_setprio(0);

        // ---- epilogue ----
        {
            int col = cb * 128 + wid * 16 + lr;
            if constexpr (LAYER == 1) {
                float bv = bias[col];
#pragma unroll
                for (int j = 0; j < 4; ++j) {
                    int row = mbase + t * 16 + lg * 4 + j;
                    if (row < rend)
                        OH[(long long)row * 256 + col] =
                            (_Float16)fmaxf(acc[j] + bv, 0.0f);
                }
            } else {
                _Float16* dp = (cb == 0) ? OH : O1h;   // g | r2
                int dcol = wid * 16 + lr;              // 0..127
#pragma unroll
                for (int j = 0; j < 4; ++j) {
                    int row = mbase + t * 16 + lg * 4 + j;
                    if (row < rend)
                        dp[(long long)row * 128 + dcol] = (_Float16)acc[j];
                }
            }
        }
        __builtin_amdgcn_s_barrier();      // readers done before buf reuse
    }
}

extern "C" void kernel_launch(void* const* d_in, const int* in_sizes, int n_in,
                              void* d_out, int out_size, void* d_ws, size_t ws_size,
                              hipStream_t stream) {
    const float* x   = (const float*)d_in[0];
    const int*   ei  = (const int*)d_in[1];     // [2, E]
    const float* W1l = (const float*)d_in[2];
    const float* b1l = (const float*)d_in[3];
    const float* W1r = (const float*)d_in[4];
    const float* W2l = (const float*)d_in[5];
    const float* b2l = (const float*)d_in[6];
    const float* W2r = (const float*)d_in[7];
    float* out = (float*)d_out;

    const int N = N_NODES, E = N_EDGES;
    const int* srcI = ei;
    const int* dstI = ei + E;

    char* ws = (char*)d_ws;
    size_t off = 0;
    auto alloc = [&](size_t bytes) {
        size_t o = off;
        off += (bytes + 511) & ~(size_t)511;
        return o;
    };
    size_t off_cnt   = alloc((size_t)N * 4);
    size_t off_offs  = alloc((size_t)(N + 1) * 4);
    size_t off_cur   = alloc((size_t)N * 4);
    size_t off_bsum  = alloc((size_t)SCAN_NB * 4);
    size_t off_boff  = alloc((size_t)SCAN_NB * 4);
    size_t off_perm  = alloc((size_t)E * 4);
    size_t off_x16   = alloc((size_t)N * 128 * 2);
    size_t off_m16   = alloc((size_t)N * 128 * 2);
    size_t off_h16   = alloc((size_t)N * 256 * 2);
    size_t off_g16   = alloc((size_t)N * 128 * 2);
    size_t off_r2    = alloc((size_t)N * 128 * 2);
    size_t off_w     = alloc((size_t)4 * 32768 * 2);
    int*      cntI = (int*)(ws + off_cnt);
    int*      offs = (int*)(ws + off_offs);
    int*      cur  = (int*)(ws + off_cur);
    int*      bsum = (int*)(ws + off_bsum);
    int*      boff = (int*)(ws + off_boff);
    int*      perm = (int*)(ws + off_perm);
    _Float16* x16  = (_Float16*)(ws + off_x16);
    _Float16* m16  = (_Float16*)(ws + off_m16);
    _Float16* h16  = (_Float16*)(ws + off_h16);
    _Float16* g16  = (_Float16*)(ws + off_g16);
    _Float16* r2h  = (_Float16*)(ws + off_r2);
    _Float16* wbuf = (_Float16*)(ws + off_w);
    const int WSZ = 32768;
    _Float16* w1l16 = wbuf;            _Float16* w1r16 = wbuf + WSZ;
    _Float16* w2l16 = wbuf + 2 * WSZ;  _Float16* w2r16 = wbuf + 3 * WSZ;

    // ---- CSR build ----
    (void)hipMemsetAsync(cntI, 0, (size_t)N * 4, stream);
    count_int_k<<<(E + 255) / 256, 256, 0, stream>>>(dstI, cntI, E);
    scan1_k<<<SCAN_NB, 256, 0, stream>>>(cntI, offs, bsum, N);
    scan2_k<<<1, 256, 0, stream>>>(bsum, boff, SCAN_NB);
    scan3_k<<<(N + 255) / 256, 256, 0, stream>>>(offs, cur, boff, N, E);
    fill_part_k<<<FILL_RANGES * FILL_SLICES, 256, 0, stream>>>(srcI, dstI, cur, perm, E);

    // ---- f16 conversions ----
    {
        int n8x = N * 16;
        cvt_f16_k<<<(n8x + 255) / 256, 256, 0, stream>>>(x, x16, n8x);
        cvt_w4_k<<<16384 / 256, 256, 0, stream>>>(W1l, W1r, W2l, W2r,
                                                  w1l16, w1r16, w2l16, w2r16);
    }

    // ---- layer 1 ----
    aggmean_k<<<(N + 15) / 16, 256, 0, stream>>>(x16, perm, offs, m16, N);
    gemm_stream_k<1><<<512, 512, 0, stream>>>(m16, x16, w1l16, w1r16,
                                              b1l, nullptr, h16, N);

    // ---- layer 2 ----
    gemm_stream_k<2><<<512, 512, 0, stream>>>(h16, h16, w2l16, w2r16,
                                              nullptr, r2h, g16, N);
    aggout_k<<<(N + 15) / 16, 256, 0, stream>>>(g16, perm, offs, r2h, b2l, out, N);
}

// Round 34
// 235.583 us; speedup vs baseline: 1.2372x; 1.0130x over previous
//
#include <hip/hip_runtime.h>

#define N_NODES 100000
#define N_EDGES 800000
#define SCAN_CHUNK 1024
#define SCAN_NB ((N_NODES + SCAN_CHUNK - 1) / SCAN_CHUNK)   // 98
#define ROWS_PER_BLK 391
#define TILES 25            // 25*16 = 400 >= 391
#define FILL_RANGES 8
#define FILL_SLICES 256
#define SLICE_SZ (N_EDGES / FILL_SLICES)   // 3125

typedef __attribute__((ext_vector_type(8))) _Float16 f16x8;
typedef __attribute__((ext_vector_type(4))) _Float16 f16x4;
typedef __attribute__((ext_vector_type(4))) float f32x4;

// ---------------- degree count ----------------
__global__ void count_int_k(const int* __restrict__ dst, int* __restrict__ cnt, int E) {
    int i = blockIdx.x * blockDim.x + threadIdx.x;
    if (i < E) atomicAdd(&cnt[dst[i]], 1);
}

// ---------------- scan pass 1 ----------------
__global__ __launch_bounds__(256) void scan1_k(const int* __restrict__ cnt,
                                               int* __restrict__ offs,
                                               int* __restrict__ bsums, int N) {
    __shared__ int s[256];
    int t = threadIdx.x;
    int base = blockIdx.x * SCAN_CHUNK + t * 4;
    int v0 = (base + 0 < N) ? cnt[base + 0] : 0;
    int v1 = (base + 1 < N) ? cnt[base + 1] : 0;
    int v2 = (base + 2 < N) ? cnt[base + 2] : 0;
    int v3 = (base + 3 < N) ? cnt[base + 3] : 0;
    int tsum = v0 + v1 + v2 + v3;
    s[t] = tsum;
    __syncthreads();
    for (int off = 1; off < 256; off <<= 1) {
        int val = (t >= off) ? s[t - off] : 0;
        __syncthreads();
        s[t] += val;
        __syncthreads();
    }
    int excl = s[t] - tsum;
    if (base + 0 < N) offs[base + 0] = excl;
    if (base + 1 < N) offs[base + 1] = excl + v0;
    if (base + 2 < N) offs[base + 2] = excl + v0 + v1;
    if (base + 3 < N) offs[base + 3] = excl + v0 + v1 + v2;
    if (t == 255) bsums[blockIdx.x] = s[255];
}

// ---------------- scan pass 2 ----------------
__global__ __launch_bounds__(256) void scan2_k(const int* __restrict__ bsums,
                                               int* __restrict__ boffs, int nb) {
    __shared__ int s[256];
    int t = threadIdx.x;
    int v = (t < nb) ? bsums[t] : 0;
    s[t] = v;
    __syncthreads();
    for (int off = 1; off < 256; off <<= 1) {
        int val = (t >= off) ? s[t - off] : 0;
        __syncthreads();
        s[t] += val;
        __syncthreads();
    }
    if (t < nb) boffs[t] = s[t] - v;
}

// ---------------- scan pass 3 ----------------
__global__ void scan3_k(int* __restrict__ offs, int* __restrict__ cursor,
                        const int* __restrict__ boffs, int N, int E) {
    int i = blockIdx.x * blockDim.x + threadIdx.x;
    if (i < N) {
        int v = offs[i] + boffs[i >> 10];
        offs[i] = v;
        cursor[i] = v;
    }
    if (i == 0) offs[N] = E;
}

// ---------------- dst-range-partitioned bucket fill (1 range per XCD) ----------------
// 2048 blocks = 8 dst-ranges x 256 edge-slices. r = bid&7 -> all blocks of
// range r land on XCD r (round-robin, bid = r mod 8): each perm window is
// written by exactly ONE XCD's L2 -> full-line write-back, no amplification.
// dst re-read 8x (halved vs 16 ranges).
__global__ __launch_bounds__(256) void fill_part_k(const int* __restrict__ src,
                                                   const int* __restrict__ dst,
                                                   int* __restrict__ cursor,
                                                   int* __restrict__ perm, int E) {
    int bid = blockIdx.x;
    int r = bid & (FILL_RANGES - 1);
    int s = bid >> 3;
    int lo = r * (N_NODES / FILL_RANGES);
    int hi = (r == FILL_RANGES - 1) ? N_NODES : lo + (N_NODES / FILL_RANGES);
    int e0 = s * SLICE_SZ;
    int e1 = min(e0 + SLICE_SZ, E);
    for (int e = e0 + (int)threadIdx.x; e < e1; e += 256) {
        int d = dst[e];
        if (d >= lo && d < hi) {
            int slot = atomicAdd(&cursor[d], 1);
            perm[slot] = src[e];
        }
    }
}

// ---------------- bulk f32 -> f16 (x features) ----------------
__global__ __launch_bounds__(256) void cvt_f16_k(const float* __restrict__ in,
                                                 _Float16* __restrict__ outp, int n8) {
    int i = blockIdx.x * blockDim.x + threadIdx.x;
    if (i >= n8) return;
    const float4* p = (const float4*)in + (long long)i * 2;
    float4 v0 = p[0], v1 = p[1];
    f16x8 h;
    h[0] = (_Float16)v0.x; h[1] = (_Float16)v0.y;
    h[2] = (_Float16)v0.z; h[3] = (_Float16)v0.w;
    h[4] = (_Float16)v1.x; h[5] = (_Float16)v1.y;
    h[6] = (_Float16)v1.z; h[7] = (_Float16)v1.w;
    *(f16x8*)&outp[(long long)i * 8] = h;
}

// ---------------- fused 4-weight f32 -> f16 ----------------
__global__ __launch_bounds__(256) void cvt_w4_k(const float* __restrict__ w0,
                                                const float* __restrict__ w1,
                                                const float* __restrict__ w2,
                                                const float* __restrict__ w3,
                                                _Float16* __restrict__ o0,
                                                _Float16* __restrict__ o1,
                                                _Float16* __restrict__ o2,
                                                _Float16* __restrict__ o3) {
    int i = blockIdx.x * blockDim.x + threadIdx.x;   // 0..16383
    int wsel = i >> 12;
    int j = i & 4095;
    const float* in; _Float16* outp;
    if (wsel == 0)      { in = w0; outp = o0; }
    else if (wsel == 1) { in = w1; outp = o1; }
    else if (wsel == 2) { in = w2; outp = o2; }
    else                { in = w3; outp = o3; }
    const float4* p = (const float4*)in + (long long)j * 2;
    float4 v0 = p[0], v1 = p[1];
    f16x8 h;
    h[0] = (_Float16)v0.x; h[1] = (_Float16)v0.y;
    h[2] = (_Float16)v0.z; h[3] = (_Float16)v0.w;
    h[4] = (_Float16)v1.x; h[5] = (_Float16)v1.y;
    h[6] = (_Float16)v1.z; h[7] = (_Float16)v1.w;
    *(f16x8*)&outp[(long long)j * 8] = h;
}

// ---------------- gather-mean, 16 lanes/node x f16x8 ----------------
__global__ __launch_bounds__(256) void aggmean_k(const _Float16* __restrict__ feat16,
                                                 const int* __restrict__ perm,
                                                 const int* __restrict__ offs,
                                                 _Float16* __restrict__ m16, int N) {
    int tid = threadIdx.x;
    int node = blockIdx.x * 16 + (tid >> 4);
    int q = tid & 15;
    if (node >= N) return;
    int beg = offs[node], end = offs[node + 1];
    float a[8], b[8];
#pragma unroll
    for (int k = 0; k < 8; k++) { a[k] = 0.0f; b[k] = 0.0f; }
    int i = beg;
    for (; i + 1 < end; i += 2) {
        f16x8 v0 = *(const f16x8*)&feat16[(long long)perm[i] * 128 + q * 8];
        f16x8 v1 = *(const f16x8*)&feat16[(long long)perm[i + 1] * 128 + q * 8];
#pragma unroll
        for (int k = 0; k < 8; k++) { a[k] += (float)v0[k]; b[k] += (float)v1[k]; }
    }
    if (i < end) {
        f16x8 v0 = *(const f16x8*)&feat16[(long long)perm[i] * 128 + q * 8];
#pragma unroll
        for (int k = 0; k < 8; k++) a[k] += (float)v0[k];
    }
    float rc = 1.0f / fmaxf((float)(end - beg), 1.0f);
    f16x8 v;
#pragma unroll
    for (int k = 0; k < 8; k++) v[k] = (_Float16)((a[k] + b[k]) * rc);
    *(f16x8*)&m16[(long long)node * 128 + q * 8] = v;
}

// ---------------- layer-2 agg fused epilogue ----------------
__global__ __launch_bounds__(256) void aggout_k(const _Float16* __restrict__ g16,
                                                const int* __restrict__ perm,
                                                const int* __restrict__ offs,
                                                const _Float16* __restrict__ r2h,
                                                const float* __restrict__ b2l,
                                                float* __restrict__ out, int N) {
    int tid = threadIdx.x;
    int node = blockIdx.x * 16 + (tid >> 4);
    int q = tid & 15;
    if (node >= N) return;
    int beg = offs[node], end = offs[node + 1];
    float a[8], b[8];
#pragma unroll
    for (int k = 0; k < 8; k++) { a[k] = 0.0f; b[k] = 0.0f; }
    int i = beg;
    for (; i + 1 < end; i += 2) {
        f16x8 v0 = *(const f16x8*)&g16[(long long)perm[i] * 128 + q * 8];
        f16x8 v1 = *(const f16x8*)&g16[(long long)perm[i + 1] * 128 + q * 8];
#pragma unroll
        for (int k = 0; k < 8; k++) { a[k] += (float)v0[k]; b[k] += (float)v1[k]; }
    }
    if (i < end) {
        f16x8 v0 = *(const f16x8*)&g16[(long long)perm[i] * 128 + q * 8];
#pragma unroll
        for (int k = 0; k < 8; k++) a[k] += (float)v0[k];
    }
    float rc = 1.0f / fmaxf((float)(end - beg), 1.0f);
    f16x8 rv = *(const f16x8*)&r2h[(long long)node * 128 + q * 8];
    float4 bv0 = ((const float4*)b2l)[q * 2];
    float4 bv1 = ((const float4*)b2l)[q * 2 + 1];
    float4 o0, o1;
    o0.x = (a[0] + b[0]) * rc + (float)rv[0] + bv0.x;
    o0.y = (a[1] + b[1]) * rc + (float)rv[1] + bv0.y;
    o0.z = (a[2] + b[2]) * rc + (float)rv[2] + bv0.z;
    o0.w = (a[3] + b[3]) * rc + (float)rv[3] + bv0.w;
    o1.x = (a[4] + b[4]) * rc + (float)rv[4] + bv1.x;
    o1.y = (a[5] + b[5]) * rc + (float)rv[5] + bv1.y;
    o1.z = (a[6] + b[6]) * rc + (float)rv[6] + bv1.z;
    o1.w = (a[7] + b[7]) * rc + (float)rv[7] + bv1.w;
    ((float4*)out)[(long long)node * 32 + q * 2]     = o0;
    ((float4*)out)[(long long)node * 32 + q * 2 + 1] = o1;
}

// ---------------- async global->LDS, 16B/lane ----------------
__device__ inline void gload16(const void* g, void* l) {
    __builtin_amdgcn_global_load_lds(
        (const __attribute__((address_space(1))) unsigned int*)g,
        (__attribute__((address_space(3))) unsigned int*)l,
        16, 0, 0);
}

// ========== col-split resident-B stream-M fp16 MFMA GEMM, 2 blocks/CU (r33) ==========
// PAIR-COLOCATED mapping: rb = bid&255, cb = bid>>8 (partners on same XCD ->
// shared A-panel L2-hit; FETCH 51->26 MB measured). B-half resident 64 KiB;
// A ring 2x8 KiB -> 80 KiB -> 2 independent blocks/CU. setprio(1) around MFMA.
template <int LAYER>
__global__ __launch_bounds__(512, 2) void gemm_stream_k(
        const _Float16* __restrict__ Ap0, const _Float16* __restrict__ Ap1,
        const _Float16* __restrict__ Bp0, const _Float16* __restrict__ Bp1,
        const float* __restrict__ bias,
        _Float16* __restrict__ O1h,
        _Float16* __restrict__ OH, int N) {
    __shared__ _Float16 Bs[128 * 256];     // 64 KiB
    __shared__ _Float16 As2[2][16 * 256];  // 2 x 8 KiB

    const int rb = blockIdx.x & 255;       // row-group
    const int cb = blockIdx.x >> 8;        // col half (partner = bid +/- 256, same XCD)
    const int mbase = rb * ROWS_PER_BLK;
    const int rend = min(mbase + ROWS_PER_BLK, N);
    const int tid = threadIdx.x;
    const int lane = tid & 63;
    const int wid = tid >> 6;            // 0..7: cols cb*128 + wid*16 .. +16
    const int lr = lane & 15, lg = lane >> 4;
    const int r2 = lane >> 5;            // 0..1
    const int scs = lane & 31;           // chunk slot 0..31

    auto STAGE_A = [&](int tt, int bi) {
        int lrow = wid * 2 + r2;               // 0..15
        int ck = scs ^ (lrow & 15);
        int gn = mbase + tt * 16 + lrow;
        if (gn < N) {
            const _Float16* src;
            if constexpr (LAYER == 1)
                src = (ck < 16) ? (Ap0 + (long long)gn * 128 + ck * 8)
                                : (Ap1 + (long long)gn * 128 + (ck - 16) * 8);
            else
                src = Ap0 + (long long)gn * 256 + ck * 8;
            gload16(src, &As2[bi][wid * 512]);
        }
    };

    // ---- resident B-half load: 64 segs of 2 local cols, 8 per wave ----
#pragma unroll
    for (int it = 0; it < 8; ++it) {
        int seg = wid * 8 + it;                // 0..63
        int lcol = seg * 2 + r2;               // 0..127
        int col = cb * 128 + lcol;             // global output col
        int ck = scs ^ (lcol & 15);            // pre-swizzled source chunk
        const _Float16* src;
        if constexpr (LAYER == 1)
            src = (ck < 16) ? (Bp0 + (long long)col * 128 + ck * 8)
                            : (Bp1 + (long long)col * 128 + (ck - 16) * 8);
        else
            src = ((cb == 0) ? Bp0 : Bp1) + (long long)lcol * 256 + ck * 8;
        gload16(src, &Bs[seg * 512]);
    }
    STAGE_A(0, 0);
    asm volatile("s_waitcnt vmcnt(0)" ::: "memory");
    __builtin_amdgcn_s_barrier();

#pragma unroll 1
    for (int t = 0; t < TILES; ++t) {
        if (t + 1 < TILES) {
            STAGE_A(t + 1, (t + 1) & 1);
            asm volatile("s_waitcnt vmcnt(1)" ::: "memory");
        } else {
            asm volatile("s_waitcnt vmcnt(0)" ::: "memory");
        }
        __builtin_amdgcn_sched_barrier(0);
        __builtin_amdgcn_s_barrier();      // tile-t data in LDS

        const _Float16* Ab = &As2[t & 1][0];
        f32x4 acc = (f32x4)0.0f;
        __builtin_amdgcn_s_setprio(1);
#pragma unroll
        for (int ks = 0; ks < 8; ++ks) {
            int c = ks * 4 + lg;               // k-chunk 0..31
            f16x8 af = *(const f16x8*)&Ab[lr * 256 + (c ^ lr) * 8];
            int lcol = wid * 16 + lr;          // local col 0..127
            f16x8 bf = *(const f16x8*)&Bs[lcol * 256 + (c ^ (lcol & 15)) * 8];
            acc = __builtin_amdgcn_mfma_f32_16x16x32_f16(af, bf, acc, 0, 0, 0);
        }
        __builtin_amdgcn_s_setprio(0);

        // ---- epilogue ----
        {
            int col = cb * 128 + wid * 16 + lr;
            if constexpr (LAYER == 1) {
                float bv = bias[col];
#pragma unroll
                for (int j = 0; j < 4; ++j) {
                    int row = mbase + t * 16 + lg * 4 + j;
                    if (row < rend)
                        OH[(long long)row * 256 + col] =
                            (_Float16)fmaxf(acc[j] + bv, 0.0f);
                }
            } else {
                _Float16* dp = (cb == 0) ? OH : O1h;   // g | r2
                int dcol = wid * 16 + lr;              // 0..127
#pragma unroll
                for (int j = 0; j < 4; ++j) {
                    int row = mbase + t * 16 + lg * 4 + j;
                    if (row < rend)
                        dp[(long long)row * 128 + dcol] = (_Float16)acc[j];
                }
            }
        }
        __builtin_amdgcn_s_barrier();      // readers done before buf reuse
    }
}

extern "C" void kernel_launch(void* const* d_in, const int* in_sizes, int n_in,
                              void* d_out, int out_size, void* d_ws, size_t ws_size,
                              hipStream_t stream) {
    const float* x   = (const float*)d_in[0];
    const int*   ei  = (const int*)d_in[1];     // [2, E]
    const float* W1l = (const float*)d_in[2];
    const float* b1l = (const float*)d_in[3];
    const float* W1r = (const float*)d_in[4];
    const float* W2l = (const float*)d_in[5];
    const float* b2l = (const float*)d_in[6];
    const float* W2r = (const float*)d_in[7];
    float* out = (float*)d_out;

    const int N = N_NODES, E = N_EDGES;
    const int* srcI = ei;
    const int* dstI = ei + E;

    char* ws = (char*)d_ws;
    size_t off = 0;
    auto alloc = [&](size_t bytes) {
        size_t o = off;
        off += (bytes + 511) & ~(size_t)511;
        return o;
    };
    size_t off_cnt   = alloc((size_t)N * 4);
    size_t off_offs  = alloc((size_t)(N + 1) * 4);
    size_t off_cur   = alloc((size_t)N * 4);
    size_t off_bsum  = alloc((size_t)SCAN_NB * 4);
    size_t off_boff  = alloc((size_t)SCAN_NB * 4);
    size_t off_perm  = alloc((size_t)E * 4);
    size_t off_x16   = alloc((size_t)N * 128 * 2);
    size_t off_m16   = alloc((size_t)N * 128 * 2);
    size_t off_h16   = alloc((size_t)N * 256 * 2);
    size_t off_g16   = alloc((size_t)N * 128 * 2);
    size_t off_r2    = alloc((size_t)N * 128 * 2);
    size_t off_w     = alloc((size_t)4 * 32768 * 2);
    int*      cntI = (int*)(ws + off_cnt);
    int*      offs = (int*)(ws + off_offs);
    int*      cur  = (int*)(ws + off_cur);
    int*      bsum = (int*)(ws + off_bsum);
    int*      boff = (int*)(ws + off_boff);
    int*      perm = (int*)(ws + off_perm);
    _Float16* x16  = (_Float16*)(ws + off_x16);
    _Float16* m16  = (_Float16*)(ws + off_m16);
    _Float16* h16  = (_Float16*)(ws + off_h16);
    _Float16* g16  = (_Float16*)(ws + off_g16);
    _Float16* r2h  = (_Float16*)(ws + off_r2);
    _Float16* wbuf = (_Float16*)(ws + off_w);
    const int WSZ = 32768;
    _Float16* w1l16 = wbuf;            _Float16* w1r16 = wbuf + WSZ;
    _Float16* w2l16 = wbuf + 2 * WSZ;  _Float16* w2r16 = wbuf + 3 * WSZ;

    // ---- CSR build ----
    (void)hipMemsetAsync(cntI, 0, (size_t)N * 4, stream);
    count_int_k<<<(E + 255) / 256, 256, 0, stream>>>(dstI, cntI, E);
    scan1_k<<<SCAN_NB, 256, 0, stream>>>(cntI, offs, bsum, N);
    scan2_k<<<1, 256, 0, stream>>>(bsum, boff, SCAN_NB);
    scan3_k<<<(N + 255) / 256, 256, 0, stream>>>(offs, cur, boff, N, E);
    fill_part_k<<<FILL_RANGES * FILL_SLICES, 256, 0, stream>>>(srcI, dstI, cur, perm, E);

    // ---- f16 conversions ----
    {
        int n8x = N * 16;
        cvt_f16_k<<<(n8x + 255) / 256, 256, 0, stream>>>(x, x16, n8x);
        cvt_w4_k<<<16384 / 256, 256, 0, stream>>>(W1l, W1r, W2l, W2r,
                                                  w1l16, w1r16, w2l16, w2r16);
    }

    // ---- layer 1 ----
    aggmean_k<<<(N + 15) / 16, 256, 0, stream>>>(x16, perm, offs, m16, N);
    gemm_stream_k<1><<<512, 512, 0, stream>>>(m16, x16, w1l16, w1r16,
                                              b1l, nullptr, h16, N);

    // ---- layer 2 ----
    gemm_stream_k<2><<<512, 512, 0, stream>>>(h16, h16, w2l16, w2r16,
                                              nullptr, r2h, g16, N);
    aggout_k<<<(N + 15) / 16, 256, 0, stream>>>(g16, perm, offs, r2h, b2l, out, N);
}

// Round 35
// 232.004 us; speedup vs baseline: 1.2563x; 1.0154x over previous
//
#include <hip/hip_runtime.h>

#define N_NODES 100000
#define N_EDGES 800000
#define SCAN_CHUNK 1024
#define SCAN_NB ((N_NODES + SCAN_CHUNK - 1) / SCAN_CHUNK)   // 98
#define ROWS_PER_BLK 391
#define TILES 25            // 25*16 = 400 >= 391
#define FILL_RANGES 8
#define FILL_SLICES 256
#define SLICE_SZ (N_EDGES / FILL_SLICES)   // 3125
// prep_k block ranges
#define CNT_BLKS ((N_EDGES + 255) / 256)            // 3125
#define CVTX_ITEMS (N_NODES * 16)                   // 1,600,000 groups of 8
#define CVTX_BLKS ((CVTX_ITEMS + 255) / 256)        // 6250
#define CVTW_BLKS 64                                // 16384 / 256
#define PREP_BLKS (CNT_BLKS + CVTX_BLKS + CVTW_BLKS)

typedef __attribute__((ext_vector_type(8))) _Float16 f16x8;
typedef __attribute__((ext_vector_type(4))) _Float16 f16x4;
typedef __attribute__((ext_vector_type(4))) float f32x4;

// ---------------- fused prep: degree count + x cvt + weight cvt ----------------
__global__ __launch_bounds__(256) void prep_k(
        const int* __restrict__ dst, int* __restrict__ cnt, int E,
        const float* __restrict__ x, _Float16* __restrict__ x16,
        const float* __restrict__ w0, const float* __restrict__ w1,
        const float* __restrict__ w2, const float* __restrict__ w3,
        _Float16* __restrict__ o0, _Float16* __restrict__ o1,
        _Float16* __restrict__ o2, _Float16* __restrict__ o3) {
    int b = blockIdx.x;
    if (b < CNT_BLKS) {
        int i = b * 256 + threadIdx.x;
        if (i < E) atomicAdd(&cnt[dst[i]], 1);
        return;
    }
    b -= CNT_BLKS;
    if (b < CVTX_BLKS) {
        int i = b * 256 + threadIdx.x;
        if (i >= CVTX_ITEMS) return;
        const float4* p = (const float4*)x + (long long)i * 2;
        float4 v0 = p[0], v1 = p[1];
        f16x8 h;
        h[0] = (_Float16)v0.x; h[1] = (_Float16)v0.y;
        h[2] = (_Float16)v0.z; h[3] = (_Float16)v0.w;
        h[4] = (_Float16)v1.x; h[5] = (_Float16)v1.y;
        h[6] = (_Float16)v1.z; h[7] = (_Float16)v1.w;
        *(f16x8*)&x16[(long long)i * 8] = h;
        return;
    }
    b -= CVTX_BLKS;
    {
        int i = b * 256 + threadIdx.x;      // 0..16383
        int wsel = i >> 12;
        int j = i & 4095;
        const float* in; _Float16* outp;
        if (wsel == 0)      { in = w0; outp = o0; }
        else if (wsel == 1) { in = w1; outp = o1; }
        else if (wsel == 2) { in = w2; outp = o2; }
        else                { in = w3; outp = o3; }
        const float4* p = (const float4*)in + (long long)j * 2;
        float4 v0 = p[0], v1 = p[1];
        f16x8 h;
        h[0] = (_Float16)v0.x; h[1] = (_Float16)v0.y;
        h[2] = (_Float16)v0.z; h[3] = (_Float16)v0.w;
        h[4] = (_Float16)v1.x; h[5] = (_Float16)v1.y;
        h[6] = (_Float16)v1.z; h[7] = (_Float16)v1.w;
        *(f16x8*)&outp[(long long)j * 8] = h;
    }
}

// ---------------- scan pass 1 ----------------
__global__ __launch_bounds__(256) void scan1_k(const int* __restrict__ cnt,
                                               int* __restrict__ offs,
                                               int* __restrict__ bsums, int N) {
    __shared__ int s[256];
    int t = threadIdx.x;
    int base = blockIdx.x * SCAN_CHUNK + t * 4;
    int v0 = (base + 0 < N) ? cnt[base + 0] : 0;
    int v1 = (base + 1 < N) ? cnt[base + 1] : 0;
    int v2 = (base + 2 < N) ? cnt[base + 2] : 0;
    int v3 = (base + 3 < N) ? cnt[base + 3] : 0;
    int tsum = v0 + v1 + v2 + v3;
    s[t] = tsum;
    __syncthreads();
    for (int off = 1; off < 256; off <<= 1) {
        int val = (t >= off) ? s[t - off] : 0;
        __syncthreads();
        s[t] += val;
        __syncthreads();
    }
    int excl = s[t] - tsum;
    if (base + 0 < N) offs[base + 0] = excl;
    if (base + 1 < N) offs[base + 1] = excl + v0;
    if (base + 2 < N) offs[base + 2] = excl + v0 + v1;
    if (base + 3 < N) offs[base + 3] = excl + v0 + v1 + v2;
    if (t == 255) bsums[blockIdx.x] = s[255];
}

// ---------------- scan pass 2 ----------------
__global__ __launch_bounds__(256) void scan2_k(const int* __restrict__ bsums,
                                               int* __restrict__ boffs, int nb) {
    __shared__ int s[256];
    int t = threadIdx.x;
    int v = (t < nb) ? bsums[t] : 0;
    s[t] = v;
    __syncthreads();
    for (int off = 1; off < 256; off <<= 1) {
        int val = (t >= off) ? s[t - off] : 0;
        __syncthreads();
        s[t] += val;
        __syncthreads();
    }
    if (t < nb) boffs[t] = s[t] - v;
}

// ---------------- scan pass 3 ----------------
__global__ void scan3_k(int* __restrict__ offs, int* __restrict__ cursor,
                        const int* __restrict__ boffs, int N, int E) {
    int i = blockIdx.x * blockDim.x + threadIdx.x;
    if (i < N) {
        int v = offs[i] + boffs[i >> 10];
        offs[i] = v;
        cursor[i] = v;
    }
    if (i == 0) offs[N] = E;
}

// ---------------- dst-range-partitioned bucket fill (1 range per XCD) ----------------
__global__ __launch_bounds__(256) void fill_part_k(const int* __restrict__ src,
                                                   const int* __restrict__ dst,
                                                   int* __restrict__ cursor,
                                                   int* __restrict__ perm, int E) {
    int bid = blockIdx.x;
    int r = bid & (FILL_RANGES - 1);
    int s = bid >> 3;
    int lo = r * (N_NODES / FILL_RANGES);
    int hi = (r == FILL_RANGES - 1) ? N_NODES : lo + (N_NODES / FILL_RANGES);
    int e0 = s * SLICE_SZ;
    int e1 = min(e0 + SLICE_SZ, E);
    for (int e = e0 + (int)threadIdx.x; e < e1; e += 256) {
        int d = dst[e];
        if (d >= lo && d < hi) {
            int slot = atomicAdd(&cursor[d], 1);
            perm[slot] = src[e];
        }
    }
}

// ---------------- gather-mean, 16 lanes/node x f16x8 ----------------
__global__ __launch_bounds__(256) void aggmean_k(const _Float16* __restrict__ feat16,
                                                 const int* __restrict__ perm,
                                                 const int* __restrict__ offs,
                                                 _Float16* __restrict__ m16, int N) {
    int tid = threadIdx.x;
    int node = blockIdx.x * 16 + (tid >> 4);
    int q = tid & 15;
    if (node >= N) return;
    int beg = offs[node], end = offs[node + 1];
    float a[8], b[8];
#pragma unroll
    for (int k = 0; k < 8; k++) { a[k] = 0.0f; b[k] = 0.0f; }
    int i = beg;
    for (; i + 1 < end; i += 2) {
        f16x8 v0 = *(const f16x8*)&feat16[(long long)perm[i] * 128 + q * 8];
        f16x8 v1 = *(const f16x8*)&feat16[(long long)perm[i + 1] * 128 + q * 8];
#pragma unroll
        for (int k = 0; k < 8; k++) { a[k] += (float)v0[k]; b[k] += (float)v1[k]; }
    }
    if (i < end) {
        f16x8 v0 = *(const f16x8*)&feat16[(long long)perm[i] * 128 + q * 8];
#pragma unroll
        for (int k = 0; k < 8; k++) a[k] += (float)v0[k];
    }
    float rc = 1.0f / fmaxf((float)(end - beg), 1.0f);
    f16x8 v;
#pragma unroll
    for (int k = 0; k < 8; k++) v[k] = (_Float16)((a[k] + b[k]) * rc);
    *(f16x8*)&m16[(long long)node * 128 + q * 8] = v;
}

// ---------------- layer-2 agg fused epilogue ----------------
__global__ __launch_bounds__(256) void aggout_k(const _Float16* __restrict__ g16,
                                                const int* __restrict__ perm,
                                                const int* __restrict__ offs,
                                                const _Float16* __restrict__ r2h,
                                                const float* __restrict__ b2l,
                                                float* __restrict__ out, int N) {
    int tid = threadIdx.x;
    int node = blockIdx.x * 16 + (tid >> 4);
    int q = tid & 15;
    if (node >= N) return;
    int beg = offs[node], end = offs[node + 1];
    float a[8], b[8];
#pragma unroll
    for (int k = 0; k < 8; k++) { a[k] = 0.0f; b[k] = 0.0f; }
    int i = beg;
    for (; i + 1 < end; i += 2) {
        f16x8 v0 = *(const f16x8*)&g16[(long long)perm[i] * 128 + q * 8];
        f16x8 v1 = *(const f16x8*)&g16[(long long)perm[i + 1] * 128 + q * 8];
#pragma unroll
        for (int k = 0; k < 8; k++) { a[k] += (float)v0[k]; b[k] += (float)v1[k]; }
    }
    if (i < end) {
        f16x8 v0 = *(const f16x8*)&g16[(long long)perm[i] * 128 + q * 8];
#pragma unroll
        for (int k = 0; k < 8; k++) a[k] += (float)v0[k];
    }
    float rc = 1.0f / fmaxf((float)(end - beg), 1.0f);
    f16x8 rv = *(const f16x8*)&r2h[(long long)node * 128 + q * 8];
    float4 bv0 = ((const float4*)b2l)[q * 2];
    float4 bv1 = ((const float4*)b2l)[q * 2 + 1];
    float4 o0, o1;
    o0.x = (a[0] + b[0]) * rc + (float)rv[0] + bv0.x;
    o0.y = (a[1] + b[1]) * rc + (float)rv[1] + bv0.y;
    o0.z = (a[2] + b[2]) * rc + (float)rv[2] + bv0.z;
    o0.w = (a[3] + b[3]) * rc + (float)rv[3] + bv0.w;
    o1.x = (a[4] + b[4]) * rc + (float)rv[4] + bv1.x;
    o1.y = (a[5] + b[5]) * rc + (float)rv[5] + bv1.y;
    o1.z = (a[6] + b[6]) * rc + (float)rv[6] + bv1.z;
    o1.w = (a[7] + b[7]) * rc + (float)rv[7] + bv1.w;
    ((float4*)out)[(long long)node * 32 + q * 2]     = o0;
    ((float4*)out)[(long long)node * 32 + q * 2 + 1] = o1;
}

// ---------------- async global->LDS, 16B/lane ----------------
__device__ inline void gload16(const void* g, void* l) {
    __builtin_amdgcn_global_load_lds(
        (const __attribute__((address_space(1))) unsigned int*)g,
        (__attribute__((address_space(3))) unsigned int*)l,
        16, 0, 0);
}

// ========== col-split resident-B stream-M fp16 MFMA GEMM, 2 blocks/CU (r33/r34) ==========
// PAIR-COLOCATED mapping: rb = bid&255, cb = bid>>8 (partners on same XCD ->
// shared A-panel L2-hit; FETCH 51->26 MB measured). B-half resident 64 KiB;
// A ring 2x8 KiB -> 80 KiB -> 2 independent blocks/CU. setprio(1) around MFMA.
template <int LAYER>
__global__ __launch_bounds__(512, 2) void gemm_stream_k(
        const _Float16* __restrict__ Ap0, const _Float16* __restrict__ Ap1,
        const _Float16* __restrict__ Bp0, const _Float16* __restrict__ Bp1,
        const float* __restrict__ bias,
        _Float16* __restrict__ O1h,
        _Float16* __restrict__ OH, int N) {
    __shared__ _Float16 Bs[128 * 256];     // 64 KiB
    __shared__ _Float16 As2[2][16 * 256];  // 2 x 8 KiB

    const int rb = blockIdx.x & 255;       // row-group
    const int cb = blockIdx.x >> 8;        // col half (partner = bid +/- 256, same XCD)
    const int mbase = rb * ROWS_PER_BLK;
    const int rend = min(mbase + ROWS_PER_BLK, N);
    const int tid = threadIdx.x;
    const int lane = tid & 63;
    const int wid = tid >> 6;            // 0..7: cols cb*128 + wid*16 .. +16
    const int lr = lane & 15, lg = lane >> 4;
    const int r2 = lane >> 5;            // 0..1
    const int scs = lane & 31;           // chunk slot 0..31

    auto STAGE_A = [&](int tt, int bi) {
        int lrow = wid * 2 + r2;               // 0..15
        int ck = scs ^ (lrow & 15);
        int gn = mbase + tt * 16 + lrow;
        if (gn < N) {
            const _Float16* src;
            if constexpr (LAYER == 1)
                src = (ck < 16) ? (Ap0 + (long long)gn * 128 + ck * 8)
                                : (Ap1 + (long long)gn * 128 + (ck - 16) * 8);
            else
                src = Ap0 + (long long)gn * 256 + ck * 8;
            gload16(src, &As2[bi][wid * 512]);
        }
    };

    // ---- resident B-half load: 64 segs of 2 local cols, 8 per wave ----
#pragma unroll
    for (int it = 0; it < 8; ++it) {
        int seg = wid * 8 + it;                // 0..63
        int lcol = seg * 2 + r2;               // 0..127
        int col = cb * 128 + lcol;             // global output col
        int ck = scs ^ (lcol & 15);            // pre-swizzled source chunk
        const _Float16* src;
        if constexpr (LAYER == 1)
            src = (ck < 16) ? (Bp0 + (long long)col * 128 + ck * 8)
                            : (Bp1 + (long long)col * 128 + (ck - 16) * 8);
        else
            src = ((cb == 0) ? Bp0 : Bp1) + (long long)lcol * 256 + ck * 8;
        gload16(src, &Bs[seg * 512]);
    }
    STAGE_A(0, 0);
    asm volatile("s_waitcnt vmcnt(0)" ::: "memory");
    __builtin_amdgcn_s_barrier();

#pragma unroll 1
    for (int t = 0; t < TILES; ++t) {
        if (t + 1 < TILES) {
            STAGE_A(t + 1, (t + 1) & 1);
            asm volatile("s_waitcnt vmcnt(1)" ::: "memory");
        } else {
            asm volatile("s_waitcnt vmcnt(0)" ::: "memory");
        }
        __builtin_amdgcn_sched_barrier(0);
        __builtin_amdgcn_s_barrier();      // tile-t data in LDS

        const _Float16* Ab = &As2[t & 1][0];
        f32x4 acc = (f32x4)0.0f;
        __builtin_amdgcn_s_setprio(1);
#pragma unroll
        for (int ks = 0; ks < 8; ++ks) {
            int c = ks * 4 + lg;               // k-chunk 0..31
            f16x8 af = *(const f16x8*)&Ab[lr * 256 + (c ^ lr) * 8];
            int lcol = wid * 16 + lr;          // local col 0..127
            f16x8 bf = *(const f16x8*)&Bs[lcol * 256 + (c ^ (lcol & 15)) * 8];
            acc = __builtin_amdgcn_mfma_f32_16x16x32_f16(af, bf, acc, 0, 0, 0);
        }
        __builtin_amdgcn_s_setprio(0);

        // ---- epilogue ----
        {
            int col = cb * 128 + wid * 16 + lr;
            if constexpr (LAYER == 1) {
                float bv = bias[col];
#pragma unroll
                for (int j = 0; j < 4; ++j) {
                    int row = mbase + t * 16 + lg * 4 + j;
                    if (row < rend)
                        OH[(long long)row * 256 + col] =
                            (_Float16)fmaxf(acc[j] + bv, 0.0f);
                }
            } else {
                _Float16* dp = (cb == 0) ? OH : O1h;   // g | r2
                int dcol = wid * 16 + lr;              // 0..127
#pragma unroll
                for (int j = 0; j < 4; ++j) {
                    int row = mbase + t * 16 + lg * 4 + j;
                    if (row < rend)
                        dp[(long long)row * 128 + dcol] = (_Float16)acc[j];
                }
            }
        }
        __builtin_amdgcn_s_barrier();      // readers done before buf reuse
    }
}

extern "C" void kernel_launch(void* const* d_in, const int* in_sizes, int n_in,
                              void* d_out, int out_size, void* d_ws, size_t ws_size,
                              hipStream_t stream) {
    const float* x   = (const float*)d_in[0];
    const int*   ei  = (const int*)d_in[1];     // [2, E]
    const float* W1l = (const float*)d_in[2];
    const float* b1l = (const float*)d_in[3];
    const float* W1r = (const float*)d_in[4];
    const float* W2l = (const float*)d_in[5];
    const float* b2l = (const float*)d_in[6];
    const float* W2r = (const float*)d_in[7];
    float* out = (float*)d_out;

    const int N = N_NODES, E = N_EDGES;
    const int* srcI = ei;
    const int* dstI = ei + E;

    char* ws = (char*)d_ws;
    size_t off = 0;
    auto alloc = [&](size_t bytes) {
        size_t o = off;
        off += (bytes + 511) & ~(size_t)511;
        return o;
    };
    size_t off_cnt   = alloc((size_t)N * 4);
    size_t off_offs  = alloc((size_t)(N + 1) * 4);
    size_t off_cur   = alloc((size_t)N * 4);
    size_t off_bsum  = alloc((size_t)SCAN_NB * 4);
    size_t off_boff  = alloc((size_t)SCAN_NB * 4);
    size_t off_perm  = alloc((size_t)E * 4);
    size_t off_x16   = alloc((size_t)N * 128 * 2);
    size_t off_m16   = alloc((size_t)N * 128 * 2);
    size_t off_h16   = alloc((size_t)N * 256 * 2);
    size_t off_g16   = alloc((size_t)N * 128 * 2);
    size_t off_r2    = alloc((size_t)N * 128 * 2);
    size_t off_w     = alloc((size_t)4 * 32768 * 2);
    int*      cntI = (int*)(ws + off_cnt);
    int*      offs = (int*)(ws + off_offs);
    int*      cur  = (int*)(ws + off_cur);
    int*      bsum = (int*)(ws + off_bsum);
    int*      boff = (int*)(ws + off_boff);
    int*      perm = (int*)(ws + off_perm);
    _Float16* x16  = (_Float16*)(ws + off_x16);
    _Float16* m16  = (_Float16*)(ws + off_m16);
    _Float16* h16  = (_Float16*)(ws + off_h16);
    _Float16* g16  = (_Float16*)(ws + off_g16);
    _Float16* r2h  = (_Float16*)(ws + off_r2);
    _Float16* wbuf = (_Float16*)(ws + off_w);
    const int WSZ = 32768;
    _Float16* w1l16 = wbuf;            _Float16* w1r16 = wbuf + WSZ;
    _Float16* w2l16 = wbuf + 2 * WSZ;  _Float16* w2r16 = wbuf + 3 * WSZ;

    // ---- fused prep: memset + (count | x cvt | weight cvt) in one dispatch ----
    (void)hipMemsetAsync(cntI, 0, (size_t)N * 4, stream);
    prep_k<<<PREP_BLKS, 256, 0, stream>>>(dstI, cntI, E, x, x16,
                                          W1l, W1r, W2l, W2r,
                                          w1l16, w1r16, w2l16, w2r16);

    // ---- CSR scan + fill ----
    scan1_k<<<SCAN_NB, 256, 0, stream>>>(cntI, offs, bsum, N);
    scan2_k<<<1, 256, 0, stream>>>(bsum, boff, SCAN_NB);
    scan3_k<<<(N + 255) / 256, 256, 0, stream>>>(offs, cur, boff, N, E);
    fill_part_k<<<FILL_RANGES * FILL_SLICES, 256, 0, stream>>>(srcI, dstI, cur, perm, E);

    // ---- layer 1 ----
    aggmean_k<<<(N + 15) / 16, 256, 0, stream>>>(x16, perm, offs, m16, N);
    gemm_stream_k<1><<<512, 512, 0, stream>>>(m16, x16, w1l16, w1r16,
                                              b1l, nullptr, h16, N);

    // ---- layer 2 ----
    gemm_stream_k<2><<<512, 512, 0, stream>>>(h16, h16, w2l16, w2r16,
                                              nullptr, r2h, g16, N);
    aggout_k<<<(N + 15) / 16, 256, 0, stream>>>(g16, perm, offs, r2h, b2l, out, N);
}

// Round 36
// 231.592 us; speedup vs baseline: 1.2586x; 1.0018x over previous
//
#include <hip/hip_runtime.h>

#define N_NODES 100000
#define N_EDGES 800000
#define SCAN_CHUNK 1024
#define SCAN_NB ((N_NODES + SCAN_CHUNK - 1) / SCAN_CHUNK)   // 98
#define ROWS_PER_BLK 391
#define TILES 25            // 25*16 = 400 >= 391
#define FILL_RANGES 8
#define FILL_SLICES 256
#define SLICE_SZ (N_EDGES / FILL_SLICES)   // 3125
// prep_k block ranges
#define CNT_BLKS (FILL_RANGES * FILL_SLICES)        // 2048, range-partitioned
#define CVTX_ITEMS (N_NODES * 16)                   // 1,600,000 groups of 8
#define CVTX_BLKS ((CVTX_ITEMS + 255) / 256)        // 6250
#define CVTW_BLKS 64                                // 16384 / 256
#define PREP_BLKS (CNT_BLKS + CVTX_BLKS + CVTW_BLKS)

typedef __attribute__((ext_vector_type(8))) _Float16 f16x8;
typedef __attribute__((ext_vector_type(4))) _Float16 f16x4;
typedef __attribute__((ext_vector_type(4))) float f32x4;

// ---------------- fused prep: partitioned degree count + x cvt + weight cvt ----------------
// Count section (bids 0..2047): r = b&7, s = b>>3 -> all blocks of range r on
// XCD r (2048 % 8 == 0): cnt atomics are L2-local, no cross-XCD latency.
__global__ __launch_bounds__(256) void prep_k(
        const int* __restrict__ dst, int* __restrict__ cnt, int E,
        const float* __restrict__ x, _Float16* __restrict__ x16,
        const float* __restrict__ w0, const float* __restrict__ w1,
        const float* __restrict__ w2, const float* __restrict__ w3,
        _Float16* __restrict__ o0, _Float16* __restrict__ o1,
        _Float16* __restrict__ o2, _Float16* __restrict__ o3) {
    int b = blockIdx.x;
    if (b < CNT_BLKS) {
        int r = b & (FILL_RANGES - 1);
        int s = b >> 3;
        int lo = r * (N_NODES / FILL_RANGES);
        int hi = (r == FILL_RANGES - 1) ? N_NODES : lo + (N_NODES / FILL_RANGES);
        int e0 = s * SLICE_SZ;
        int e1 = min(e0 + SLICE_SZ, E);
        for (int e = e0 + (int)threadIdx.x; e < e1; e += 256) {
            int d = dst[e];
            if (d >= lo && d < hi) atomicAdd(&cnt[d], 1);
        }
        return;
    }
    b -= CNT_BLKS;
    if (b < CVTX_BLKS) {
        int i = b * 256 + threadIdx.x;
        if (i >= CVTX_ITEMS) return;
        const float4* p = (const float4*)x + (long long)i * 2;
        float4 v0 = p[0], v1 = p[1];
        f16x8 h;
        h[0] = (_Float16)v0.x; h[1] = (_Float16)v0.y;
        h[2] = (_Float16)v0.z; h[3] = (_Float16)v0.w;
        h[4] = (_Float16)v1.x; h[5] = (_Float16)v1.y;
        h[6] = (_Float16)v1.z; h[7] = (_Float16)v1.w;
        *(f16x8*)&x16[(long long)i * 8] = h;
        return;
    }
    b -= CVTX_BLKS;
    {
        int i = b * 256 + threadIdx.x;      // 0..16383
        int wsel = i >> 12;
        int j = i & 4095;
        const float* in; _Float16* outp;
        if (wsel == 0)      { in = w0; outp = o0; }
        else if (wsel == 1) { in = w1; outp = o1; }
        else if (wsel == 2) { in = w2; outp = o2; }
        else                { in = w3; outp = o3; }
        const float4* p = (const float4*)in + (long long)j * 2;
        float4 v0 = p[0], v1 = p[1];
        f16x8 h;
        h[0] = (_Float16)v0.x; h[1] = (_Float16)v0.y;
        h[2] = (_Float16)v0.z; h[3] = (_Float16)v0.w;
        h[4] = (_Float16)v1.x; h[5] = (_Float16)v1.y;
        h[6] = (_Float16)v1.z; h[7] = (_Float16)v1.w;
        *(f16x8*)&outp[(long long)j * 8] = h;
    }
}

// ---------------- scan pass 1 ----------------
__global__ __launch_bounds__(256) void scan1_k(const int* __restrict__ cnt,
                                               int* __restrict__ offs,
                                               int* __restrict__ bsums, int N) {
    __shared__ int s[256];
    int t = threadIdx.x;
    int base = blockIdx.x * SCAN_CHUNK + t * 4;
    int v0 = (base + 0 < N) ? cnt[base + 0] : 0;
    int v1 = (base + 1 < N) ? cnt[base + 1] : 0;
    int v2 = (base + 2 < N) ? cnt[base + 2] : 0;
    int v3 = (base + 3 < N) ? cnt[base + 3] : 0;
    int tsum = v0 + v1 + v2 + v3;
    s[t] = tsum;
    __syncthreads();
    for (int off = 1; off < 256; off <<= 1) {
        int val = (t >= off) ? s[t - off] : 0;
        __syncthreads();
        s[t] += val;
        __syncthreads();
    }
    int excl = s[t] - tsum;
    if (base + 0 < N) offs[base + 0] = excl;
    if (base + 1 < N) offs[base + 1] = excl + v0;
    if (base + 2 < N) offs[base + 2] = excl + v0 + v1;
    if (base + 3 < N) offs[base + 3] = excl + v0 + v1 + v2;
    if (t == 255) bsums[blockIdx.x] = s[255];
}

// ---------------- scan pass 2 ----------------
__global__ __launch_bounds__(256) void scan2_k(const int* __restrict__ bsums,
                                               int* __restrict__ boffs, int nb) {
    __shared__ int s[256];
    int t = threadIdx.x;
    int v = (t < nb) ? bsums[t] : 0;
    s[t] = v;
    __syncthreads();
    for (int off = 1; off < 256; off <<= 1) {
        int val = (t >= off) ? s[t - off] : 0;
        __syncthreads();
        s[t] += val;
        __syncthreads();
    }
    if (t < nb) boffs[t] = s[t] - v;
}

// ---------------- scan pass 3 ----------------
__global__ void scan3_k(int* __restrict__ offs, int* __restrict__ cursor,
                        const int* __restrict__ boffs, int N, int E) {
    int i = blockIdx.x * blockDim.x + threadIdx.x;
    if (i < N) {
        int v = offs[i] + boffs[i >> 10];
        offs[i] = v;
        cursor[i] = v;
    }
    if (i == 0) offs[N] = E;
}

// ---------------- dst-range-partitioned bucket fill (1 range per XCD) ----------------
__global__ __launch_bounds__(256) void fill_part_k(const int* __restrict__ src,
                                                   const int* __restrict__ dst,
                                                   int* __restrict__ cursor,
                                                   int* __restrict__ perm, int E) {
    int bid = blockIdx.x;
    int r = bid & (FILL_RANGES - 1);
    int s = bid >> 3;
    int lo = r * (N_NODES / FILL_RANGES);
    int hi = (r == FILL_RANGES - 1) ? N_NODES : lo + (N_NODES / FILL_RANGES);
    int e0 = s * SLICE_SZ;
    int e1 = min(e0 + SLICE_SZ, E);
    for (int e = e0 + (int)threadIdx.x; e < e1; e += 256) {
        int d = dst[e];
        if (d >= lo && d < hi) {
            int slot = atomicAdd(&cursor[d], 1);
            perm[slot] = src[e];
        }
    }
}

// ---------------- gather-mean, 16 lanes/node x f16x8 ----------------
__global__ __launch_bounds__(256) void aggmean_k(const _Float16* __restrict__ feat16,
                                                 const int* __restrict__ perm,
                                                 const int* __restrict__ offs,
                                                 _Float16* __restrict__ m16, int N) {
    int tid = threadIdx.x;
    int node = blockIdx.x * 16 + (tid >> 4);
    int q = tid & 15;
    if (node >= N) return;
    int beg = offs[node], end = offs[node + 1];
    float a[8], b[8];
#pragma unroll
    for (int k = 0; k < 8; k++) { a[k] = 0.0f; b[k] = 0.0f; }
    int i = beg;
    for (; i + 1 < end; i += 2) {
        f16x8 v0 = *(const f16x8*)&feat16[(long long)perm[i] * 128 + q * 8];
        f16x8 v1 = *(const f16x8*)&feat16[(long long)perm[i + 1] * 128 + q * 8];
#pragma unroll
        for (int k = 0; k < 8; k++) { a[k] += (float)v0[k]; b[k] += (float)v1[k]; }
    }
    if (i < end) {
        f16x8 v0 = *(const f16x8*)&feat16[(long long)perm[i] * 128 + q * 8];
#pragma unroll
        for (int k = 0; k < 8; k++) a[k] += (float)v0[k];
    }
    float rc = 1.0f / fmaxf((float)(end - beg), 1.0f);
    f16x8 v;
#pragma unroll
    for (int k = 0; k < 8; k++) v[k] = (_Float16)((a[k] + b[k]) * rc);
    *(f16x8*)&m16[(long long)node * 128 + q * 8] = v;
}

// ---------------- layer-2 agg fused epilogue ----------------
__global__ __launch_bounds__(256) void aggout_k(const _Float16* __restrict__ g16,
                                                const int* __restrict__ perm,
                                                const int* __restrict__ offs,
                                                const _Float16* __restrict__ r2h,
                                                const float* __restrict__ b2l,
                                                float* __restrict__ out, int N) {
    int tid = threadIdx.x;
    int node = blockIdx.x * 16 + (tid >> 4);
    int q = tid & 15;
    if (node >= N) return;
    int beg = offs[node], end = offs[node + 1];
    float a[8], b[8];
#pragma unroll
    for (int k = 0; k < 8; k++) { a[k] = 0.0f; b[k] = 0.0f; }
    int i = beg;
    for (; i + 1 < end; i += 2) {
        f16x8 v0 = *(const f16x8*)&g16[(long long)perm[i] * 128 + q * 8];
        f16x8 v1 = *(const f16x8*)&g16[(long long)perm[i + 1] * 128 + q * 8];
#pragma unroll
        for (int k = 0; k < 8; k++) { a[k] += (float)v0[k]; b[k] += (float)v1[k]; }
    }
    if (i < end) {
        f16x8 v0 = *(const f16x8*)&g16[(long long)perm[i] * 128 + q * 8];
#pragma unroll
        for (int k = 0; k < 8; k++) a[k] += (float)v0[k];
    }
    float rc = 1.0f / fmaxf((float)(end - beg), 1.0f);
    f16x8 rv = *(const f16x8*)&r2h[(long long)node * 128 + q * 8];
    float4 bv0 = ((const float4*)b2l)[q * 2];
    float4 bv1 = ((const float4*)b2l)[q * 2 + 1];
    float4 o0, o1;
    o0.x = (a[0] + b[0]) * rc + (float)rv[0] + bv0.x;
    o0.y = (a[1] + b[1]) * rc + (float)rv[1] + bv0.y;
    o0.z = (a[2] + b[2]) * rc + (float)rv[2] + bv0.z;
    o0.w = (a[3] + b[3]) * rc + (float)rv[3] + bv0.w;
    o1.x = (a[4] + b[4]) * rc + (float)rv[4] + bv1.x;
    o1.y = (a[5] + b[5]) * rc + (float)rv[5] + bv1.y;
    o1.z = (a[6] + b[6]) * rc + (float)rv[6] + bv1.z;
    o1.w = (a[7] + b[7]) * rc + (float)rv[7] + bv1.w;
    ((float4*)out)[(long long)node * 32 + q * 2]     = o0;
    ((float4*)out)[(long long)node * 32 + q * 2 + 1] = o1;
}

// ---------------- async global->LDS, 16B/lane ----------------
__device__ inline void gload16(const void* g, void* l) {
    __builtin_amdgcn_global_load_lds(
        (const __attribute__((address_space(1))) unsigned int*)g,
        (__attribute__((address_space(3))) unsigned int*)l,
        16, 0, 0);
}

// ========== col-split resident-B stream-M fp16 MFMA GEMM, 2 blocks/CU (r33/r34) ==========
template <int LAYER>
__global__ __launch_bounds__(512, 2) void gemm_stream_k(
        const _Float16* __restrict__ Ap0, const _Float16* __restrict__ Ap1,
        const _Float16* __restrict__ Bp0, const _Float16* __restrict__ Bp1,
        const float* __restrict__ bias,
        _Float16* __restrict__ O1h,
        _Float16* __restrict__ OH, int N) {
    __shared__ _Float16 Bs[128 * 256];     // 64 KiB
    __shared__ _Float16 As2[2][16 * 256];  // 2 x 8 KiB

    const int rb = blockIdx.x & 255;       // row-group
    const int cb = blockIdx.x >> 8;        // col half (partner = bid +/- 256, same XCD)
    const int mbase = rb * ROWS_PER_BLK;
    const int rend = min(mbase + ROWS_PER_BLK, N);
    const int tid = threadIdx.x;
    const int lane = tid & 63;
    const int wid = tid >> 6;            // 0..7: cols cb*128 + wid*16 .. +16
    const int lr = lane & 15, lg = lane >> 4;
    const int r2 = lane >> 5;            // 0..1
    const int scs = lane & 31;           // chunk slot 0..31

    auto STAGE_A = [&](int tt, int bi) {
        int lrow = wid * 2 + r2;               // 0..15
        int ck = scs ^ (lrow & 15);
        int gn = mbase + tt * 16 + lrow;
        if (gn < N) {
            const _Float16* src;
            if constexpr (LAYER == 1)
                src = (ck < 16) ? (Ap0 + (long long)gn * 128 + ck * 8)
                                : (Ap1 + (long long)gn * 128 + (ck - 16) * 8);
            else
                src = Ap0 + (long long)gn * 256 + ck * 8;
            gload16(src, &As2[bi][wid * 512]);
        }
    };

    // ---- resident B-half load: 64 segs of 2 local cols, 8 per wave ----
#pragma unroll
    for (int it = 0; it < 8; ++it) {
        int seg = wid * 8 + it;                // 0..63
        int lcol = seg * 2 + r2;               // 0..127
        int col = cb * 128 + lcol;             // global output col
        int ck = scs ^ (lcol & 15);            // pre-swizzled source chunk
        const _Float16* src;
        if constexpr (LAYER == 1)
            src = (ck < 16) ? (Bp0 + (long long)col * 128 + ck * 8)
                            : (Bp1 + (long long)col * 128 + (ck - 16) * 8);
        else
            src = ((cb == 0) ? Bp0 : Bp1) + (long long)lcol * 256 + ck * 8;
        gload16(src, &Bs[seg * 512]);
    }
    STAGE_A(0, 0);
    asm volatile("s_waitcnt vmcnt(0)" ::: "memory");
    __builtin_amdgcn_s_barrier();

#pragma unroll 1
    for (int t = 0; t < TILES; ++t) {
        if (t + 1 < TILES) {
            STAGE_A(t + 1, (t + 1) & 1);
            asm volatile("s_waitcnt vmcnt(1)" ::: "memory");
        } else {
            asm volatile("s_waitcnt vmcnt(0)" ::: "memory");
        }
        __builtin_amdgcn_sched_barrier(0);
        __builtin_amdgcn_s_barrier();      // tile-t data in LDS

        const _Float16* Ab = &As2[t & 1][0];
        f32x4 acc = (f32x4)0.0f;
        __builtin_amdgcn_s_setprio(1);
#pragma unroll
        for (int ks = 0; ks < 8; ++ks) {
            int c = ks * 4 + lg;               // k-chunk 0..31
            f16x8 af = *(const f16x8*)&Ab[lr * 256 + (c ^ lr) * 8];
            int lcol = wid * 16 + lr;          // local col 0..127
            f16x8 bf = *(const f16x8*)&Bs[lcol * 256 + (c ^ (lcol & 15)) * 8];
            acc = __builtin_amdgcn_mfma_f32_16x16x32_f16(af, bf, acc, 0, 0, 0);
        }
        __builtin_amdgcn_s_setprio(0);

        // ---- epilogue ----
        {
            int col = cb * 128 + wid * 16 + lr;
            if constexpr (LAYER == 1) {
                float bv = bias[col];
#pragma unroll
                for (int j = 0; j < 4; ++j) {
                    int row = mbase + t * 16 + lg * 4 + j;
                    if (row < rend)
                        OH[(long long)row * 256 + col] =
                            (_Float16)fmaxf(acc[j] + bv, 0.0f);
                }
            } else {
                _Float16* dp = (cb == 0) ? OH : O1h;   // g | r2
                int dcol = wid * 16 + lr;              // 0..127
#pragma unroll
                for (int j = 0; j < 4; ++j) {
                    int row = mbase + t * 16 + lg * 4 + j;
                    if (row < rend)
                        dp[(long long)row * 128 + dcol] = (_Float16)acc[j];
                }
            }
        }
        __builtin_amdgcn_s_barrier();      // readers done before buf reuse
    }
}

extern "C" void kernel_launch(void* const* d_in, const int* in_sizes, int n_in,
                              void* d_out, int out_size, void* d_ws, size_t ws_size,
                              hipStream_t stream) {
    const float* x   = (const float*)d_in[0];
    const int*   ei  = (const int*)d_in[1];     // [2, E]
    const float* W1l = (const float*)d_in[2];
    const float* b1l = (const float*)d_in[3];
    const float* W1r = (const float*)d_in[4];
    const float* W2l = (const float*)d_in[5];
    const float* b2l = (const float*)d_in[6];
    const float* W2r = (const float*)d_in[7];
    float* out = (float*)d_out;

    const int N = N_NODES, E = N_EDGES;
    const int* srcI = ei;
    const int* dstI = ei + E;

    char* ws = (char*)d_ws;
    size_t off = 0;
    auto alloc = [&](size_t bytes) {
        size_t o = off;
        off += (bytes + 511) & ~(size_t)511;
        return o;
    };
    size_t off_cnt   = alloc((size_t)N * 4);
    size_t off_offs  = alloc((size_t)(N + 1) * 4);
    size_t off_cur   = alloc((size_t)N * 4);
    size_t off_bsum  = alloc((size_t)SCAN_NB * 4);
    size_t off_boff  = alloc((size_t)SCAN_NB * 4);
    size_t off_perm  = alloc((size_t)E * 4);
    size_t off_x16   = alloc((size_t)N * 128 * 2);
    size_t off_m16   = alloc((size_t)N * 128 * 2);
    size_t off_h16   = alloc((size_t)N * 256 * 2);
    size_t off_g16   = alloc((size_t)N * 128 * 2);
    size_t off_r2    = alloc((size_t)N * 128 * 2);
    size_t off_w     = alloc((size_t)4 * 32768 * 2);
    int*      cntI = (int*)(ws + off_cnt);
    int*      offs = (int*)(ws + off_offs);
    int*      cur  = (int*)(ws + off_cur);
    int*      bsum = (int*)(ws + off_bsum);
    int*      boff = (int*)(ws + off_boff);
    int*      perm = (int*)(ws + off_perm);
    _Float16* x16  = (_Float16*)(ws + off_x16);
    _Float16* m16  = (_Float16*)(ws + off_m16);
    _Float16* h16  = (_Float16*)(ws + off_h16);
    _Float16* g16  = (_Float16*)(ws + off_g16);
    _Float16* r2h  = (_Float16*)(ws + off_r2);
    _Float16* wbuf = (_Float16*)(ws + off_w);
    const int WSZ = 32768;
    _Float16* w1l16 = wbuf;            _Float16* w1r16 = wbuf + WSZ;
    _Float16* w2l16 = wbuf + 2 * WSZ;  _Float16* w2r16 = wbuf + 3 * WSZ;

    // ---- fused prep: memset + (partitioned count | x cvt | weight cvt) ----
    (void)hipMemsetAsync(cntI, 0, (size_t)N * 4, stream);
    prep_k<<<PREP_BLKS, 256, 0, stream>>>(dstI, cntI, E, x, x16,
                                          W1l, W1r, W2l, W2r,
                                          w1l16, w1r16, w2l16, w2r16);

    // ---- CSR scan + fill ----
    scan1_k<<<SCAN_NB, 256, 0, stream>>>(cntI, offs, bsum, N);
    scan2_k<<<1, 256, 0, stream>>>(bsum, boff, SCAN_NB);
    scan3_k<<<(N + 255) / 256, 256, 0, stream>>>(offs, cur, boff, N, E);
    fill_part_k<<<FILL_RANGES * FILL_SLICES, 256, 0, stream>>>(srcI, dstI, cur, perm, E);

    // ---- layer 1 ----
    aggmean_k<<<(N + 15) / 16, 256, 0, stream>>>(x16, perm, offs, m16, N);
    gemm_stream_k<1><<<512, 512, 0, stream>>>(m16, x16, w1l16, w1r16,
                                              b1l, nullptr, h16, N);

    // ---- layer 2 ----
    gemm_stream_k<2><<<512, 512, 0, stream>>>(h16, h16, w2l16, w2r16,
                                              nullptr, r2h, g16, N);
    aggout_k<<<(N + 15) / 16, 256, 0, stream>>>(g16, perm, offs, r2h, b2l, out, N);
}